// Round 6
// baseline (745.749 us; speedup 1.0000x reference)
//
#include <hip/hip_runtime.h>
#include <hip/hip_bf16.h>
#include <cstdint>

#define DEV_INLINE __device__ __forceinline__

// problem constants
constexpr int N0n = 100000, N1n = 25000, N2n = 6250;
constexpr int E0n = 800000, E1n = 200000, E2n = 50000;
constexpr int NT  = N0n + N1n + N2n;     // 131250 concatenated node space
constexpr int ET  = E0n + E1n + E2n;     // 1050000 concatenated edge space
constexpr int Bn  = 2;

DEV_INLINE float lrelu(float x) { return x > 0.f ? x : 0.01f * x; }

// ---- bf16 V-tables. r5 decisive test: halving bytes left time invariant ->
// gather kernels are ADDRESS-throughput bound, not byte/line bound. r6 lever:
// halve gather lane-addresses (16B/lane = 8 bf16 ch) and kill per-edge csr
// broadcast loads via LDS staging (~1 lane-addr/edge, coalesced).
DEV_INLINE ushort f2bf(float f) {
    uint32_t u = __builtin_bit_cast(uint32_t, f);
    u += 0x7FFFu + ((u >> 16) & 1u);       // round-to-nearest-even
    return (ushort)(u >> 16);
}
DEV_INLINE float bflo(uint32_t w) { return __builtin_bit_cast(float, w << 16); }
DEV_INLINE float bfhi(uint32_t w) { return __builtin_bit_cast(float, w & 0xFFFF0000u); }

// acc[k] += relu(u[k] + v[k]) for 8 bf16 channels packed in a uint4
DEV_INLINE void acc_bf8(float* acc, const float* u, const uint4 w) {
    acc[0] += fmaxf(u[0] + bflo(w.x), 0.f);
    acc[1] += fmaxf(u[1] + bfhi(w.x), 0.f);
    acc[2] += fmaxf(u[2] + bflo(w.y), 0.f);
    acc[3] += fmaxf(u[3] + bfhi(w.y), 0.f);
    acc[4] += fmaxf(u[4] + bflo(w.z), 0.f);
    acc[5] += fmaxf(u[5] + bfhi(w.z), 0.f);
    acc[6] += fmaxf(u[6] + bflo(w.w), 0.f);
    acc[7] += fmaxf(u[7] + bfhi(w.w), 0.f);
}

// ---------------- CSR build (3 graphs concatenated) ----------------

__global__ __launch_bounds__(256) void k_deg_count(const int* __restrict__ g0,
                                                   const int* __restrict__ g1,
                                                   const int* __restrict__ g2,
                                                   int* __restrict__ deg) {
    int e = blockIdx.x * 256 + threadIdx.x;
    int gd = -1;
    if (e < E0n)                gd = g0[E0n + e] % N0n;
    else if (e < E0n + E1n)     gd = N0n + (g1[E1n + (e - E0n)] % N1n);
    else if (e < ET)            gd = N0n + N1n + (g2[E2n + (e - E0n - E1n)] % N2n);
    if (gd >= 0 && gd < NT) atomicAdd(&deg[gd], 1);
}

constexpr int SCAN_CHUNK = 2048;
constexpr int NCHUNK = (NT + SCAN_CHUNK - 1) / SCAN_CHUNK;   // 65

__global__ __launch_bounds__(256) void k_scan1(const int* __restrict__ deg,
                                               int* __restrict__ out,
                                               int* __restrict__ partials) {
    __shared__ int sums[256];
    const int chunk = blockIdx.x, t = threadIdx.x;
    const int base = chunk * SCAN_CHUNK + t * 8;
    int v[8]; int s = 0;
#pragma unroll
    for (int i = 0; i < 8; i++) { int idx = base + i; v[i] = (idx < NT) ? deg[idx] : 0; s += v[i]; }
    int val = s;
    sums[t] = val; __syncthreads();
    for (int off = 1; off < 256; off <<= 1) {
        int y = (t >= off) ? sums[t - off] : 0;
        __syncthreads();
        val += y; sums[t] = val;
        __syncthreads();
    }
    const int excl = val - s;
    if (t == 255) partials[chunk] = val;
    int run = excl;
#pragma unroll
    for (int i = 0; i < 8; i++) { int idx = base + i; if (idx < NT) out[idx] = run; run += v[i]; }
}

// scan2 folded in: each block redundantly prefix-sums the 65 partials in LDS.
__global__ __launch_bounds__(256) void k_scan3(const int* __restrict__ partials,
                                               int* __restrict__ offsets) {
    __shared__ int s[NCHUNK];
    __shared__ int pre[NCHUNK + 1];
    const int t = threadIdx.x;
    if (t < NCHUNK) s[t] = partials[t];
    __syncthreads();
    if (t == 0) {
        int run = 0;
        for (int i = 0; i < NCHUNK; i++) { pre[i] = run; run += s[i]; }
        pre[NCHUNK] = run;
    }
    __syncthreads();
    const int idx = blockIdx.x * 256 + t;
    if (idx < NT) offsets[idx] += pre[idx / SCAN_CHUNK];
    if (idx == 0) offsets[NT] = pre[NCHUNK];   // == ET
}

// Partitioned fill: per dst segment, sources valid for the NEXT level's unpool
// (src < nnz of that level) go at the front; invalid sources fill from the back.
// cursor[] afterwards == per-node valid-source count (consumed by fused aggs).
__global__ __launch_bounds__(256) void k_csr_fill(const int* __restrict__ g0,
                                                  const int* __restrict__ g1,
                                                  const int* __restrict__ g2,
                                                  const int* __restrict__ offsets,
                                                  int* __restrict__ cursor,
                                                  int* __restrict__ bcur,
                                                  int* __restrict__ csr) {
    int e = blockIdx.x * 256 + threadIdx.x;
    int src, gd; bool front;
    if (e < E0n)            { src = g0[e] % N0n;      gd = g0[E0n + e] % N0n;                 front = src < N1n; }
    else if (e < E0n + E1n) { int le = e - E0n;       src = g1[le] % N1n; gd = N0n + (g1[E1n + le] % N1n); front = src < N2n; }
    else if (e < ET)        { int le = e - E0n - E1n; src = g2[le] % N2n; gd = N0n + N1n + (g2[E2n + le] % N2n); front = true; }
    else return;
    int pos = front ? offsets[gd] + atomicAdd(&cursor[gd], 1)
                    : offsets[gd + 1] - 1 - atomicAdd(&bcur[gd], 1);
    if (pos >= 0 && pos < ET) csr[pos] = src;   // local src id
}

// ---------------- latent MLP: z -> x0 [N2, B, 128] ----------------

__global__ __launch_bounds__(256) void k_latent(const float* __restrict__ z,
                                                const float* __restrict__ W1,
                                                const float* __restrict__ b1,
                                                const float* __restrict__ W2,
                                                const float* __restrict__ b2,
                                                float* __restrict__ x0) {
    __shared__ float col[64];
    const int t = threadIdx.x;
    const int b = t >> 7, l = t & 127;
    const float zv = z[b * 128 + l];
    float h1[64];
#pragma unroll
    for (int k = 0; k < 64; k++) h1[k] = lrelu(zv * W1[k] + b1[k]);
    for (int nn = 0; nn < 8; nn++) {
        const int n = blockIdx.x * 8 + nn;
        if (n >= N2n) break;                 // uniform across block
        if (t < 64) col[t] = W2[t * N2n + n];
        __syncthreads();
        float s = b2[n];
#pragma unroll
        for (int k = 0; k < 64; k++) s += h1[k] * col[k];
        x0[((size_t)n * Bn + b) * 128 + l] = s;
        __syncthreads();
    }
}

// ---------------- dual GEMM: U = x(Wa-Wb)+b (fp32), V = x*Wb (bf16) ----------------
// 128x64 tile, 8x4 per thread. x: [Mrows,K] fp32; W: [2K,COUT] fp32; compact out.

template <int K, int COUT>
__global__ __launch_bounds__(256) void k_gemm_uv(const float* __restrict__ x,
                                                 const float* __restrict__ W,
                                                 const float* __restrict__ bias,
                                                 float* __restrict__ U,
                                                 ushort* __restrict__ Vb,
                                                 int Mrows) {
    constexpr int TM = 128, TN = 64, TK = 32;
    __shared__ float xs[TK][TM + 4];
    __shared__ float wd[TK][TN];
    __shared__ float wb[TK][TN];
    const int t = threadIdx.x;
    const int row0 = blockIdx.x * TM;
    const int col0 = blockIdx.y * TN;
    const int tc = (t & 15) * 4;        // 16 col groups * 4
    const int tr = (t >> 4) * 8;        // 16 row groups * 8
    const int lrow = t >> 1;            // x-load: 128 rows, 2 thr/row
    const int lseg = (t & 1) * 16;      // x-load: 16 consecutive k
    const int wrow = t >> 3;            // w-load: 32 k rows
    const int wseg = (t & 7) * 8;       // w-load: 8 cols
    float accU[8][4] = {}, accV[8][4] = {};

    for (int k0 = 0; k0 < K; k0 += TK) {
        __syncthreads();
        {   // x tile: 4 float4 per thread, transposed store
            float4 a[4] = {{0,0,0,0},{0,0,0,0},{0,0,0,0},{0,0,0,0}};
            const int gr = row0 + lrow;
            if (gr < Mrows) {
                const float4* p = (const float4*)(x + (size_t)gr * K + k0 + lseg);
                a[0] = p[0]; a[1] = p[1]; a[2] = p[2]; a[3] = p[3];
            }
#pragma unroll
            for (int q = 0; q < 4; q++) {
                xs[lseg + 4 * q + 0][lrow] = a[q].x;
                xs[lseg + 4 * q + 1][lrow] = a[q].y;
                xs[lseg + 4 * q + 2][lrow] = a[q].z;
                xs[lseg + 4 * q + 3][lrow] = a[q].w;
            }
        }
        {   // W tiles: rows [0,K) = Wa (mult x_i), rows [K,2K) = Wb (mult x_j - x_i)
            const float* wa = W + (size_t)(k0 + wrow) * COUT + col0 + wseg;
            const float* wbp = wa + (size_t)K * COUT;
            float fa[8], fb[8];
            *(float4*)&fa[0] = ((const float4*)wa)[0];
            *(float4*)&fa[4] = ((const float4*)wa)[1];
            *(float4*)&fb[0] = ((const float4*)wbp)[0];
            *(float4*)&fb[4] = ((const float4*)wbp)[1];
#pragma unroll
            for (int i = 0; i < 8; i++) {
                wd[wrow][wseg + i] = fa[i] - fb[i];
                wb[wrow][wseg + i] = fb[i];
            }
        }
        __syncthreads();
#pragma unroll
        for (int kk = 0; kk < TK; ++kk) {
            const float4 a0 = *(const float4*)&xs[kk][tr];
            const float4 a1 = *(const float4*)&xs[kk][tr + 4];
            const float4 d = *(const float4*)&wd[kk][tc];
            const float4 e = *(const float4*)&wb[kk][tc];
            const float av[8] = {a0.x, a0.y, a0.z, a0.w, a1.x, a1.y, a1.z, a1.w};
            const float dv[4] = {d.x, d.y, d.z, d.w};
            const float ev[4] = {e.x, e.y, e.z, e.w};
#pragma unroll
            for (int i = 0; i < 8; i++)
#pragma unroll
                for (int j = 0; j < 4; j++) {
                    accU[i][j] += av[i] * dv[j];
                    accV[i][j] += av[i] * ev[j];
                }
        }
    }
    float bf4[4];
#pragma unroll
    for (int j = 0; j < 4; j++) bf4[j] = bias[col0 + tc + j];
#pragma unroll
    for (int i = 0; i < 8; i++) {
        const int r = row0 + tr + i;
        if (r < Mrows) {
            const size_t orow = (size_t)r * COUT + col0 + tc;
            float4 uo = {accU[i][0] + bf4[0], accU[i][1] + bf4[1],
                         accU[i][2] + bf4[2], accU[i][3] + bf4[3]};
            *(float4*)(U + orow) = uo;
            ushort4 vh = {f2bf(accV[i][0]), f2bf(accV[i][1]),
                          f2bf(accV[i][2]), f2bf(accV[i][3])};
            *(ushort4*)(Vb + orow) = vh;
        }
    }
}

// ---------------- dense edge agg: out[i] = mean_j relu(u_i + v_j) ----------------
// bf16 V, 8 ch/lane (16B gathers), csr staged in LDS (coalesced).

template <int C, int CAP>
__global__ __launch_bounds__(256) void k_edge_agg(const float* __restrict__ U,
                                                  const ushort* __restrict__ Vb,
                                                  const int* __restrict__ offsets,
                                                  const int* __restrict__ csr,
                                                  int nbase, int nnodes,
                                                  float* __restrict__ out) {
    constexpr int TPN = C / 8;          // lanes per node (8 bf16 ch each)
    constexpr int NPB = 256 / TPN;      // nodes per block
    __shared__ int soff[NPB + 1];
    __shared__ int scsr[CAP];
    const int t = threadIdx.x;
    const int n0 = blockIdx.x * NPB;
    if (t <= NPB) {
        const int idx = min(n0 + t, nnodes);
        soff[t] = max(0, min(offsets[nbase + idx], ET));
    }
    __syncthreads();
    const int base = soff[0];
    const int tot = min(soff[NPB] - base, CAP);
    for (int k = t; k < tot; k += 256) scsr[k] = csr[base + k];
    __syncthreads();

    const int sub = t / TPN;
    const int c8 = (t % TPN) * 8;
    const int i = n0 + sub;
    if (i >= nnodes) return;
    const int beg = soff[sub];
    const int end = max(soff[sub + 1], beg);
    float u[8], acc[8] = {};
    *(float4*)&u[0] = *(const float4*)&U[(size_t)i * C + c8];
    *(float4*)&u[4] = *(const float4*)&U[(size_t)i * C + c8 + 4];
    int e = beg;
    for (; e + 4 <= end; e += 4) {
        const int o = e - base;
        const int j0 = (o     < tot) ? scsr[o]     : csr[e];
        const int j1 = (o + 1 < tot) ? scsr[o + 1] : csr[e + 1];
        const int j2 = (o + 2 < tot) ? scsr[o + 2] : csr[e + 2];
        const int j3 = (o + 3 < tot) ? scsr[o + 3] : csr[e + 3];
        const uint4 w0 = *(const uint4*)&Vb[(size_t)j0 * C + c8];
        const uint4 w1 = *(const uint4*)&Vb[(size_t)j1 * C + c8];
        const uint4 w2 = *(const uint4*)&Vb[(size_t)j2 * C + c8];
        const uint4 w3 = *(const uint4*)&Vb[(size_t)j3 * C + c8];
        acc_bf8(acc, u, w0); acc_bf8(acc, u, w1);
        acc_bf8(acc, u, w2); acc_bf8(acc, u, w3);
    }
    for (; e < end; ++e) {
        const int o = e - base;
        const int j = (o < tot) ? scsr[o] : csr[e];
        const uint4 w = *(const uint4*)&Vb[(size_t)j * C + c8];
        acc_bf8(acc, u, w);
    }
    const int dg = end - beg;
    const float inv = 1.f / (float)(dg > 0 ? dg : 1);
    float4 o0 = {acc[0] * inv, acc[1] * inv, acc[2] * inv, acc[3] * inv};
    float4 o1 = {acc[4] * inv, acc[5] * inv, acc[6] * inv, acc[7] * inv};
    *(float4*)&out[(size_t)i * C + c8] = o0;
    *(float4*)&out[(size_t)i * C + c8 + 4] = o1;
}

// ---------------- fused dual agg (Res_up output) ----------------
// Partitioned CSR: [beg, beg+vc) valid gathers; remaining cnt edges -> cnt*relu(u).
// bf16 V tables, 8 ch/lane, LDS-staged csr.

template <int C, int CAP>
__global__ __launch_bounds__(256) void k_edge_agg_fused(const float* __restrict__ U2,
                                                        const ushort* __restrict__ V2b,
                                                        const float* __restrict__ Usk,
                                                        const ushort* __restrict__ Vskb,
                                                        const float* __restrict__ b2,
                                                        const float* __restrict__ bsk,
                                                        const int* __restrict__ offsets,
                                                        const int* __restrict__ vcnt,
                                                        const int* __restrict__ csr,
                                                        int nbase, int nnodes, int nnz,
                                                        float* __restrict__ out) {
    constexpr int COUTc = C / Bn;
    constexpr int TPN = C / 8;
    constexpr int NPB = 256 / TPN;
    __shared__ int soff[NPB + 1];
    __shared__ int svc[NPB];
    __shared__ int scsr[CAP];
    const int t = threadIdx.x;
    const int n0 = blockIdx.x * NPB;
    if (t <= NPB) {
        const int idx = min(n0 + t, nnodes);
        soff[t] = max(0, min(offsets[nbase + idx], ET));
    }
    if (t < NPB) svc[t] = (n0 + t < nnodes) ? vcnt[nbase + n0 + t] : 0;
    __syncthreads();
    const int base = soff[0];
    const int tot = min(soff[NPB] - base, CAP);
    for (int k = t; k < tot; k += 256) scsr[k] = csr[base + k];
    __syncthreads();

    const int sub = t / TPN;
    const int c8 = (t % TPN) * 8;
    const int i = n0 + sub;
    if (i >= nnodes) return;
    const int beg = soff[sub];
    const int end = max(soff[sub + 1], beg);
    const int dg = end - beg;
    const int vc = max(0, min(svc[sub], dg));
    const int vend = beg + vc;
    const int cb = c8 & (COUTc - 1);
    float u2[8], usk[8];
    if (i < nnz) {
        *(float4*)&u2[0]  = *(const float4*)&U2[(size_t)i * C + c8];
        *(float4*)&u2[4]  = *(const float4*)&U2[(size_t)i * C + c8 + 4];
        *(float4*)&usk[0] = *(const float4*)&Usk[(size_t)i * C + c8];
        *(float4*)&usk[4] = *(const float4*)&Usk[(size_t)i * C + c8 + 4];
    } else {
        *(float4*)&u2[0]  = *(const float4*)&b2[cb];
        *(float4*)&u2[4]  = *(const float4*)&b2[cb + 4];
        *(float4*)&usk[0] = *(const float4*)&bsk[cb];
        *(float4*)&usk[4] = *(const float4*)&bsk[cb + 4];
    }
    float a2[8] = {}, ask[8] = {};
    int e = beg;
    for (; e + 4 <= vend; e += 4) {
        const int o = e - base;
        const int j0 = (o     < tot) ? scsr[o]     : csr[e];
        const int j1 = (o + 1 < tot) ? scsr[o + 1] : csr[e + 1];
        const int j2 = (o + 2 < tot) ? scsr[o + 2] : csr[e + 2];
        const int j3 = (o + 3 < tot) ? scsr[o + 3] : csr[e + 3];
        const uint4 p0 = *(const uint4*)&V2b[(size_t)j0 * C + c8];
        const uint4 p1 = *(const uint4*)&V2b[(size_t)j1 * C + c8];
        const uint4 p2 = *(const uint4*)&V2b[(size_t)j2 * C + c8];
        const uint4 p3 = *(const uint4*)&V2b[(size_t)j3 * C + c8];
        const uint4 q0 = *(const uint4*)&Vskb[(size_t)j0 * C + c8];
        const uint4 q1 = *(const uint4*)&Vskb[(size_t)j1 * C + c8];
        const uint4 q2 = *(const uint4*)&Vskb[(size_t)j2 * C + c8];
        const uint4 q3 = *(const uint4*)&Vskb[(size_t)j3 * C + c8];
        acc_bf8(a2, u2, p0); acc_bf8(a2, u2, p1); acc_bf8(a2, u2, p2); acc_bf8(a2, u2, p3);
        acc_bf8(ask, usk, q0); acc_bf8(ask, usk, q1); acc_bf8(ask, usk, q2); acc_bf8(ask, usk, q3);
    }
    for (; e < vend; ++e) {
        const int o = e - base;
        const int j = (o < tot) ? scsr[o] : csr[e];
        const uint4 pv = *(const uint4*)&V2b[(size_t)j * C + c8];
        const uint4 qv = *(const uint4*)&Vskb[(size_t)j * C + c8];
        acc_bf8(a2, u2, pv); acc_bf8(ask, usk, qv);
    }
    const int cnt = dg - vc;                  // edges with j >= nnz: v = 0
    if (cnt > 0) {
        const float fc = (float)cnt;
#pragma unroll
        for (int k = 0; k < 8; k++) {
            a2[k]  += fc * fmaxf(u2[k], 0.f);
            ask[k] += fc * fmaxf(usk[k], 0.f);
        }
    }
    const float inv = 1.f / (float)(dg > 0 ? dg : 1);
    float o0[8];
#pragma unroll
    for (int k = 0; k < 8; k++) o0[k] = lrelu((a2[k] + ask[k]) * inv);
    *(float4*)&out[(size_t)i * C + c8]     = *(float4*)&o0[0];
    *(float4*)&out[(size_t)i * C + c8 + 4] = *(float4*)&o0[4];
}

// ---------------- fused final agg + decoder MLP + LayerNorm(3) ----------------
// 16 nodes/block, 16 lanes/node (8 bf16 ch), LDS-staged csr; 32-row decoder.

__global__ __launch_bounds__(256) void k_agg_dec(const float* __restrict__ U,
                                                 const ushort* __restrict__ Vb,
                                                 const int* __restrict__ offsets,
                                                 const int* __restrict__ csr,
                                                 const float* __restrict__ Wd1,
                                                 const float* __restrict__ bd1,
                                                 const float* __restrict__ Wd2,
                                                 const float* __restrict__ bd2,
                                                 const float* __restrict__ gamma,
                                                 const float* __restrict__ beta,
                                                 float* __restrict__ out) {
    constexpr int C = 128;
    constexpr int CAP = 768;
    __shared__ float w1[2048];          // Wd1 [64,32]
    __shared__ float w2[96];            // Wd2 [32,3]
    __shared__ float sb1[32], sb2[3], sg[3], sbt[3];
    __shared__ float xs[32 * 66];       // 32 (n,b) rows of 64, stride 66
    __shared__ float hs[32][33];        // h1 per row
    __shared__ int soff[17];
    __shared__ int scsr[CAP];
    const int t = threadIdx.x;
    for (int i = t; i < 2048; i += 256) w1[i] = Wd1[i];
    if (t < 96) w2[t] = Wd2[t];
    if (t < 32) sb1[t] = bd1[t];
    if (t < 3) { sb2[t] = bd2[t]; sg[t] = gamma[t]; sbt[t] = beta[t]; }

    const int n0 = blockIdx.x * 16;
    if (t <= 16) {
        const int idx = min(n0 + t, N0n);
        soff[t] = max(0, min(offsets[idx], ET));
    }
    __syncthreads();
    const int base = soff[0];
    const int tot = min(soff[16] - base, CAP);
    for (int k = t; k < tot; k += 256) scsr[k] = csr[base + k];
    __syncthreads();

    // --- agg phase: 16 nodes/block, 16 thr/node, 8 bf16 ch/lane ---
    const int sub = t >> 4;
    const int c8 = (t & 15) * 8;        // channel = b*64 + k
    const int i0 = n0 + sub;
    float r[8] = {};
    if (i0 < N0n) {
        const int beg = soff[sub];
        const int end = max(soff[sub + 1], beg);
        float u[8], acc[8] = {};
        *(float4*)&u[0] = *(const float4*)&U[(size_t)i0 * C + c8];
        *(float4*)&u[4] = *(const float4*)&U[(size_t)i0 * C + c8 + 4];
        int e = beg;
        for (; e + 4 <= end; e += 4) {
            const int o = e - base;
            const int j0 = (o     < tot) ? scsr[o]     : csr[e];
            const int j1 = (o + 1 < tot) ? scsr[o + 1] : csr[e + 1];
            const int j2 = (o + 2 < tot) ? scsr[o + 2] : csr[e + 2];
            const int j3 = (o + 3 < tot) ? scsr[o + 3] : csr[e + 3];
            const uint4 w0 = *(const uint4*)&Vb[(size_t)j0 * C + c8];
            const uint4 w1v = *(const uint4*)&Vb[(size_t)j1 * C + c8];
            const uint4 w2v = *(const uint4*)&Vb[(size_t)j2 * C + c8];
            const uint4 w3 = *(const uint4*)&Vb[(size_t)j3 * C + c8];
            acc_bf8(acc, u, w0); acc_bf8(acc, u, w1v);
            acc_bf8(acc, u, w2v); acc_bf8(acc, u, w3);
        }
        for (; e < end; ++e) {
            const int o = e - base;
            const int j = (o < tot) ? scsr[o] : csr[e];
            const uint4 w = *(const uint4*)&Vb[(size_t)j * C + c8];
            acc_bf8(acc, u, w);
        }
        const int dg = end - beg;
        const float inv = 1.f / (float)(dg > 0 ? dg : 1);
#pragma unroll
        for (int k = 0; k < 8; k++) r[k] = acc[k] * inv;
    }
    // stage into LDS: row = sub*2 + b, col = k (8 entries per lane)
    {
        const int rrow = sub * 2 + (c8 >> 6);
        const int rk = c8 & 63;
        float* xp = &xs[rrow * 66 + rk];
#pragma unroll
        for (int k = 0; k < 8; k++) xp[k] = r[k];
    }
    __syncthreads();

    // --- decoder: 32 rows x 8 threads; thread computes h1[l8+8m], m=0..3 ---
    const int drow = t >> 3;
    const int l8 = t & 7;
    float h1[4] = {sb1[l8], sb1[l8 + 8], sb1[l8 + 16], sb1[l8 + 24]};
    const float* xrow = &xs[drow * 66];
#pragma unroll 8
    for (int k = 0; k < 64; k++) {
        const float xk = xrow[k];
        h1[0] += xk * w1[k * 32 + l8];
        h1[1] += xk * w1[k * 32 + l8 + 8];
        h1[2] += xk * w1[k * 32 + l8 + 16];
        h1[3] += xk * w1[k * 32 + l8 + 24];
    }
    hs[drow][l8]      = lrelu(h1[0]);
    hs[drow][l8 + 8]  = lrelu(h1[1]);
    hs[drow][l8 + 16] = lrelu(h1[2]);
    hs[drow][l8 + 24] = lrelu(h1[3]);
    __syncthreads();

    // --- h2 + LN: one thread per row ---
    if (t < 32) {
        const int node = t >> 1, b = t & 1;
        const int n = n0 + node;
        if (n < N0n) {
            float h2[3];
#pragma unroll
            for (int j = 0; j < 3; j++) {
                float s = sb2[j];
#pragma unroll
                for (int c = 0; c < 32; c++) s += hs[t][c] * w2[c * 3 + j];
                h2[j] = s;
            }
            const float mu = (h2[0] + h2[1] + h2[2]) * (1.f / 3.f);
            const float d0 = h2[0] - mu, d1 = h2[1] - mu, d2 = h2[2] - mu;
            const float var = (d0 * d0 + d1 * d1 + d2 * d2) * (1.f / 3.f);
            const float inv = rsqrtf(var + 1e-5f);
            const size_t ob = (size_t)b * N0n * 3 + (size_t)n * 3;
            out[ob + 0] = d0 * inv * sg[0] + sbt[0];
            out[ob + 1] = d1 * inv * sg[1] + sbt[1];
            out[ob + 2] = d2 * inv * sg[2] + sbt[2];
        }
    }
}

// ---------------- launch ----------------

extern "C" void kernel_launch(void* const* d_in, const int* in_sizes, int n_in,
                              void* d_out, int out_size, void* d_ws, size_t ws_size,
                              hipStream_t stream) {
    (void)in_sizes; (void)n_in; (void)out_size; (void)ws_size;
    const float* z   = (const float*)d_in[0];
    const int* g0    = (const int*)d_in[1];
    const int* g1    = (const int*)d_in[2];
    const int* g2    = (const int*)d_in[3];
    const float* W_up1 = (const float*)d_in[6];
    const float* b_up1 = (const float*)d_in[7];
    const float* W_up2 = (const float*)d_in[8];
    const float* b_up2 = (const float*)d_in[9];
    const float* Wb    = (const float*)d_in[10];
    const float* bb    = (const float*)d_in[11];
    const float* l0_W1 = (const float*)d_in[12];
    const float* l0_b1 = (const float*)d_in[13];
    const float* l0_W2 = (const float*)d_in[14];
    const float* l0_b2 = (const float*)d_in[15];
    const float* l0_Wsk = (const float*)d_in[16];
    const float* l0_bsk = (const float*)d_in[17];
    const float* l1_W1 = (const float*)d_in[18];
    const float* l1_b1 = (const float*)d_in[19];
    const float* l1_W2 = (const float*)d_in[20];
    const float* l1_b2 = (const float*)d_in[21];
    const float* l1_Wsk = (const float*)d_in[22];
    const float* l1_bsk = (const float*)d_in[23];
    const float* Wf    = (const float*)d_in[24];
    const float* bf_   = (const float*)d_in[25];
    const float* Wd1   = (const float*)d_in[26];
    const float* bd1   = (const float*)d_in[27];
    const float* Wd2   = (const float*)d_in[28];
    const float* bd2   = (const float*)d_in[29];
    const float* gamma = (const float*)d_in[30];
    const float* beta  = (const float*)d_in[31];

    char* p = (char*)d_ws;
    auto alloc = [&](size_t bytes) -> char* {
        char* r = p; p += (bytes + 255) & ~(size_t)255; return r;
    };
    int* offsets  = (int*)alloc((size_t)(NT + 1) * 4);
    int* partials = (int*)alloc((size_t)NCHUNK * 4);
    int* degcur   = (int*)alloc((size_t)3 * NT * 4);
    int* deg = degcur; int* cursor = degcur + NT; int* bcur = degcur + 2 * NT;
    int* csr = (int*)alloc((size_t)ET * 4);

    // pooled slabs: A,B,C = 12.8M floats (51.2 MB) each, D = 3.2M floats.
    // V regions are bf16 (half-occupied float granules) — offsets unchanged.
    constexpr size_t SLOT = (size_t)N0n * Bn * 64;   // 12.8M floats
    constexpr size_t M1 = 1600000;                    // 1.6M-float granule
    float* A = (float*)alloc(SLOT * 4);
    float* B = (float*)alloc(SLOT * 4);
    float* C = (float*)alloc(SLOT * 4);
    float* D = (float*)alloc((size_t)N1n * Bn * 64 * 4);

    // --- CSR build ---
    hipMemsetAsync(degcur, 0, (size_t)3 * NT * 4, stream);
    k_deg_count<<<(ET + 255) / 256, 256, 0, stream>>>(g0, g1, g2, deg);
    k_scan1<<<NCHUNK, 256, 0, stream>>>(deg, offsets, partials);
    k_scan3<<<(NT + 255) / 256, 256, 0, stream>>>(partials, offsets);
    k_csr_fill<<<(ET + 255) / 256, 256, 0, stream>>>(g0, g1, g2, offsets, cursor, bcur, csr);

    const int nb2 = N0n + N1n;   // g2 node base in offsets
    const int nb1 = N0n;         // g1 node base

    // --- latent -> x0 [N2,B,128] @ A[0,M1) ---
    float* x0 = A;
    k_latent<<<(N2n + 7) / 8, 256, 0, stream>>>(z, W_up1, b_up1, W_up2, b_up2, x0);

    // --- conv1 (g2, 128->256): U@A[M1,3M1) Vb@A[3M1,..) -> xc1 @ A[5M1,7M1) ---
    float* xc1 = A + 5 * M1;
    k_gemm_uv<128, 256><<<dim3(98, 4), 256, 0, stream>>>(x0, Wb, bb,
                                                         A + M1, (ushort*)(A + 3 * M1), N2n * Bn);
    k_edge_agg<512, 256><<<(N2n + 3) / 4, 256, 0, stream>>>(A + M1, (const ushort*)(A + 3 * M1),
                                                            offsets, csr, nb2, N2n, xc1);

    // --- l0_W1 (g2, 256->64): U@A[7M1,+.5) Vb@A[7.5M1,..) -> t1 @ A[0,M1) (x0 dead) ---
    float* t1 = A;
    k_gemm_uv<256, 64><<<dim3(98, 1), 256, 0, stream>>>(xc1, l0_W1, l0_b1,
                                                        A + 7 * M1, (ushort*)(A + 7 * M1 + 800000),
                                                        N2n * Bn);
    k_edge_agg<128, 768><<<(N2n + 15) / 16, 256, 0, stream>>>(A + 7 * M1,
                                                              (const ushort*)(A + 7 * M1 + 800000),
                                                              offsets, csr, nb2, N2n, t1);

    // --- l0_W2 GEMM (64->128): t1 -> U2@B[0,M1) V2b@B[M1,..) ---
    k_gemm_uv<64, 128><<<dim3(98, 2), 256, 0, stream>>>(t1, l0_W2, l0_b2,
                                                        B, (ushort*)(B + M1), N2n * Bn);
    // --- skip0 GEMM (256->128): xc1 -> Usk@B[2M1,3M1) Vskb@B[3M1,..) ---
    k_gemm_uv<256, 128><<<dim3(98, 2), 256, 0, stream>>>(xc1, l0_Wsk, l0_bsk,
                                                         B + 2 * M1, (ushort*)(B + 3 * M1), N2n * Bn);
    // --- fused layer0 agg (g1, C=256, nnz=N2n): -> x1 @ B[4M1,8M1) ---
    float* x1 = B + 4 * M1;
    k_edge_agg_fused<256, 512><<<(N1n + 7) / 8, 256, 0, stream>>>(B, (const ushort*)(B + M1),
                                                                  B + 2 * M1, (const ushort*)(B + 3 * M1),
                                                                  l0_b2, l0_bsk, offsets, cursor, csr,
                                                                  nb1, N1n, N2n, x1);

    // --- l1_W1 (g1, 128->64): U@A[0,2M1) Vb@A[2M1,..) -> t2 @ D ---
    float* t2 = D;
    k_gemm_uv<128, 64><<<dim3(391, 1), 256, 0, stream>>>(x1, l1_W1, l1_b1,
                                                         A, (ushort*)(A + 2 * M1), N1n * Bn);
    k_edge_agg<128, 768><<<(N1n + 15) / 16, 256, 0, stream>>>(A, (const ushort*)(A + 2 * M1),
                                                              offsets, csr, nb1, N1n, t2);

    // --- l1_W2 GEMM (64->64): t2 -> U2@A[0,2M1) V2b@A[2M1,..) ---
    k_gemm_uv<64, 64><<<dim3(391, 1), 256, 0, stream>>>(t2, l1_W2, l1_b2,
                                                        A, (ushort*)(A + 2 * M1), N1n * Bn);
    // --- skip1 GEMM (128->64): x1 -> Usk@A[4M1,6M1) Vskb@A[6M1,..) ---
    k_gemm_uv<128, 64><<<dim3(391, 1), 256, 0, stream>>>(x1, l1_Wsk, l1_bsk,
                                                         A + 4 * M1, (ushort*)(A + 6 * M1), N1n * Bn);
    // --- fused layer1 agg (g0, C=128, nnz=N1n): -> x2 @ C ---
    float* x2 = C;
    k_edge_agg_fused<128, 768><<<(N0n + 15) / 16, 256, 0, stream>>>(A, (const ushort*)(A + 2 * M1),
                                                                    A + 4 * M1, (const ushort*)(A + 6 * M1),
                                                                    l1_b2, l1_bsk, offsets, cursor, csr,
                                                                    0, N0n, N1n, x2);

    // --- final conv (g0, 64->64): x2 -> Uf@A (full) Vfb@B -> fused agg+decoder+LN ---
    k_gemm_uv<64, 64><<<dim3(1563, 1), 256, 0, stream>>>(x2, Wf, bf_, A, (ushort*)B, N0n * Bn);
    k_agg_dec<<<(N0n + 15) / 16, 256, 0, stream>>>(A, (const ushort*)B, offsets, csr,
                                                   Wd1, bd1, Wd2, bd2, gamma, beta,
                                                   (float*)d_out);
}

// Round 7
// 623.403 us; speedup vs baseline: 1.1963x; 1.1963x over previous
//
#include <hip/hip_runtime.h>
#include <hip/hip_bf16.h>
#include <cstdint>

#define DEV_INLINE __device__ __forceinline__

// problem constants
constexpr int N0n = 100000, N1n = 25000, N2n = 6250;
constexpr int E0n = 800000, E1n = 200000, E2n = 50000;
constexpr int NT  = N0n + N1n + N2n;     // 131250 concatenated node space
constexpr int ET  = E0n + E1n + E2n;     // 1050000 concatenated edge space
constexpr int Bn  = 2;

DEV_INLINE float lrelu(float x) { return x > 0.f ? x : 0.01f * x; }

// ---- bf16 V-tables (r5/r6). Gather kernels proved address-throughput bound;
// r6's 8ch/lane + LDS-csr cut k_agg_dec 89.5->72.6us. r7: GEMM occupancy —
// TM templated (128/64/32) so small-M GEMMs fill the 256-CU chip (was 98 blocks).
DEV_INLINE ushort f2bf(float f) {
    uint32_t u = __builtin_bit_cast(uint32_t, f);
    u += 0x7FFFu + ((u >> 16) & 1u);       // round-to-nearest-even
    return (ushort)(u >> 16);
}
DEV_INLINE float bflo(uint32_t w) { return __builtin_bit_cast(float, w << 16); }
DEV_INLINE float bfhi(uint32_t w) { return __builtin_bit_cast(float, w & 0xFFFF0000u); }

// acc[k] += relu(u[k] + v[k]) for 8 bf16 channels packed in a uint4
DEV_INLINE void acc_bf8(float* acc, const float* u, const uint4 w) {
    acc[0] += fmaxf(u[0] + bflo(w.x), 0.f);
    acc[1] += fmaxf(u[1] + bfhi(w.x), 0.f);
    acc[2] += fmaxf(u[2] + bflo(w.y), 0.f);
    acc[3] += fmaxf(u[3] + bfhi(w.y), 0.f);
    acc[4] += fmaxf(u[4] + bflo(w.z), 0.f);
    acc[5] += fmaxf(u[5] + bfhi(w.z), 0.f);
    acc[6] += fmaxf(u[6] + bflo(w.w), 0.f);
    acc[7] += fmaxf(u[7] + bfhi(w.w), 0.f);
}

// ---------------- CSR build (3 graphs concatenated) ----------------

__global__ __launch_bounds__(256) void k_deg_count(const int* __restrict__ g0,
                                                   const int* __restrict__ g1,
                                                   const int* __restrict__ g2,
                                                   int* __restrict__ deg) {
    int e = blockIdx.x * 256 + threadIdx.x;
    int gd = -1;
    if (e < E0n)                gd = g0[E0n + e] % N0n;
    else if (e < E0n + E1n)     gd = N0n + (g1[E1n + (e - E0n)] % N1n);
    else if (e < ET)            gd = N0n + N1n + (g2[E2n + (e - E0n - E1n)] % N2n);
    if (gd >= 0 && gd < NT) atomicAdd(&deg[gd], 1);
}

constexpr int SCAN_CHUNK = 2048;
constexpr int NCHUNK = (NT + SCAN_CHUNK - 1) / SCAN_CHUNK;   // 65

__global__ __launch_bounds__(256) void k_scan1(const int* __restrict__ deg,
                                               int* __restrict__ out,
                                               int* __restrict__ partials) {
    __shared__ int sums[256];
    const int chunk = blockIdx.x, t = threadIdx.x;
    const int base = chunk * SCAN_CHUNK + t * 8;
    int v[8]; int s = 0;
#pragma unroll
    for (int i = 0; i < 8; i++) { int idx = base + i; v[i] = (idx < NT) ? deg[idx] : 0; s += v[i]; }
    int val = s;
    sums[t] = val; __syncthreads();
    for (int off = 1; off < 256; off <<= 1) {
        int y = (t >= off) ? sums[t - off] : 0;
        __syncthreads();
        val += y; sums[t] = val;
        __syncthreads();
    }
    const int excl = val - s;
    if (t == 255) partials[chunk] = val;
    int run = excl;
#pragma unroll
    for (int i = 0; i < 8; i++) { int idx = base + i; if (idx < NT) out[idx] = run; run += v[i]; }
}

// scan2 folded in: each block redundantly prefix-sums the 65 partials in LDS.
__global__ __launch_bounds__(256) void k_scan3(const int* __restrict__ partials,
                                               int* __restrict__ offsets) {
    __shared__ int s[NCHUNK];
    __shared__ int pre[NCHUNK + 1];
    const int t = threadIdx.x;
    if (t < NCHUNK) s[t] = partials[t];
    __syncthreads();
    if (t == 0) {
        int run = 0;
        for (int i = 0; i < NCHUNK; i++) { pre[i] = run; run += s[i]; }
        pre[NCHUNK] = run;
    }
    __syncthreads();
    const int idx = blockIdx.x * 256 + t;
    if (idx < NT) offsets[idx] += pre[idx / SCAN_CHUNK];
    if (idx == 0) offsets[NT] = pre[NCHUNK];   // == ET
}

// Partitioned fill: per dst segment, sources valid for the NEXT level's unpool
// (src < nnz of that level) go at the front; invalid sources fill from the back.
// cursor[] afterwards == per-node valid-source count (consumed by fused aggs).
__global__ __launch_bounds__(256) void k_csr_fill(const int* __restrict__ g0,
                                                  const int* __restrict__ g1,
                                                  const int* __restrict__ g2,
                                                  const int* __restrict__ offsets,
                                                  int* __restrict__ cursor,
                                                  int* __restrict__ bcur,
                                                  int* __restrict__ csr) {
    int e = blockIdx.x * 256 + threadIdx.x;
    int src, gd; bool front;
    if (e < E0n)            { src = g0[e] % N0n;      gd = g0[E0n + e] % N0n;                 front = src < N1n; }
    else if (e < E0n + E1n) { int le = e - E0n;       src = g1[le] % N1n; gd = N0n + (g1[E1n + le] % N1n); front = src < N2n; }
    else if (e < ET)        { int le = e - E0n - E1n; src = g2[le] % N2n; gd = N0n + N1n + (g2[E2n + le] % N2n); front = true; }
    else return;
    int pos = front ? offsets[gd] + atomicAdd(&cursor[gd], 1)
                    : offsets[gd + 1] - 1 - atomicAdd(&bcur[gd], 1);
    if (pos >= 0 && pos < ET) csr[pos] = src;   // local src id
}

// ---------------- latent MLP: z -> x0 [N2, B, 128] ----------------

__global__ __launch_bounds__(256) void k_latent(const float* __restrict__ z,
                                                const float* __restrict__ W1,
                                                const float* __restrict__ b1,
                                                const float* __restrict__ W2,
                                                const float* __restrict__ b2,
                                                float* __restrict__ x0) {
    __shared__ float col[64];
    const int t = threadIdx.x;
    const int b = t >> 7, l = t & 127;
    const float zv = z[b * 128 + l];
    float h1[64];
#pragma unroll
    for (int k = 0; k < 64; k++) h1[k] = lrelu(zv * W1[k] + b1[k]);
    for (int nn = 0; nn < 8; nn++) {
        const int n = blockIdx.x * 8 + nn;
        if (n >= N2n) break;                 // uniform across block
        if (t < 64) col[t] = W2[t * N2n + n];
        __syncthreads();
        float s = b2[n];
#pragma unroll
        for (int k = 0; k < 64; k++) s += h1[k] * col[k];
        x0[((size_t)n * Bn + b) * 128 + l] = s;
        __syncthreads();
    }
}

// ---------------- dual GEMM: U = x(Wa-Wb)+b (fp32), V = x*Wb (bf16) ----------------
// TM templated (128/64/32): small-M GEMMs need small tiles to fill 256 CUs
// (r7: l0_W1 launched 98 blocks -> 62% of the chip idle). Accumulation order
// (k0 asc, kk asc) identical across TM -> bitwise-same outputs.

template <int K, int COUT, int TM>
__global__ __launch_bounds__(256) void k_gemm_uv(const float* __restrict__ x,
                                                 const float* __restrict__ W,
                                                 const float* __restrict__ bias,
                                                 float* __restrict__ U,
                                                 ushort* __restrict__ Vb,
                                                 int Mrows) {
    constexpr int TN = 64, TK = 32;
    constexpr int RPT = TM / 16;        // rows per thread: 8 / 4 / 2
    __shared__ float xs[TK][TM + 4];
    __shared__ float wd[TK][TN];
    __shared__ float wb[TK][TN];
    const int t = threadIdx.x;
    const int row0 = blockIdx.x * TM;
    const int col0 = blockIdx.y * TN;
    const int tc = (t & 15) * 4;        // 16 col groups * 4
    const int tr = (t >> 4) * RPT;      // 16 row groups * RPT
    const int wrow = t >> 3;            // w-load: 32 k rows
    const int wseg = (t & 7) * 8;       // w-load: 8 cols
    float accU[RPT][4] = {}, accV[RPT][4] = {};

    for (int k0 = 0; k0 < K; k0 += TK) {
        __syncthreads();
        if constexpr (TM == 128) {      // 2 thr/row, 16 consecutive k each
            const int lrow = t >> 1, lseg = (t & 1) * 16;
            float4 a[4] = {{0,0,0,0},{0,0,0,0},{0,0,0,0},{0,0,0,0}};
            const int gr = row0 + lrow;
            if (gr < Mrows) {
                const float4* p = (const float4*)(x + (size_t)gr * K + k0 + lseg);
                a[0] = p[0]; a[1] = p[1]; a[2] = p[2]; a[3] = p[3];
            }
#pragma unroll
            for (int q = 0; q < 4; q++) {
                xs[lseg + 4 * q + 0][lrow] = a[q].x;
                xs[lseg + 4 * q + 1][lrow] = a[q].y;
                xs[lseg + 4 * q + 2][lrow] = a[q].z;
                xs[lseg + 4 * q + 3][lrow] = a[q].w;
            }
        } else if constexpr (TM == 64) { // 4 thr/row, 8 consecutive k each
            const int lrow = t >> 2, lseg = (t & 3) * 8;
            float4 a0 = {0,0,0,0}, a1 = {0,0,0,0};
            const int gr = row0 + lrow;
            if (gr < Mrows) {
                const float4* p = (const float4*)(x + (size_t)gr * K + k0 + lseg);
                a0 = p[0]; a1 = p[1];
            }
            xs[lseg + 0][lrow] = a0.x; xs[lseg + 1][lrow] = a0.y;
            xs[lseg + 2][lrow] = a0.z; xs[lseg + 3][lrow] = a0.w;
            xs[lseg + 4][lrow] = a1.x; xs[lseg + 5][lrow] = a1.y;
            xs[lseg + 6][lrow] = a1.z; xs[lseg + 7][lrow] = a1.w;
        } else {                         // TM == 32: 8 thr/row, 4 k each
            const int lrow = t >> 3, lseg = (t & 7) * 4;
            float4 a0 = {0,0,0,0};
            const int gr = row0 + lrow;
            if (gr < Mrows) a0 = *(const float4*)(x + (size_t)gr * K + k0 + lseg);
            xs[lseg + 0][lrow] = a0.x; xs[lseg + 1][lrow] = a0.y;
            xs[lseg + 2][lrow] = a0.z; xs[lseg + 3][lrow] = a0.w;
        }
        {   // W tiles: rows [0,K) = Wa (mult x_i), rows [K,2K) = Wb (mult x_j - x_i)
            const float* wa = W + (size_t)(k0 + wrow) * COUT + col0 + wseg;
            const float* wbp = wa + (size_t)K * COUT;
            float fa[8], fb[8];
            *(float4*)&fa[0] = ((const float4*)wa)[0];
            *(float4*)&fa[4] = ((const float4*)wa)[1];
            *(float4*)&fb[0] = ((const float4*)wbp)[0];
            *(float4*)&fb[4] = ((const float4*)wbp)[1];
#pragma unroll
            for (int i = 0; i < 8; i++) {
                wd[wrow][wseg + i] = fa[i] - fb[i];
                wb[wrow][wseg + i] = fb[i];
            }
        }
        __syncthreads();
#pragma unroll
        for (int kk = 0; kk < TK; ++kk) {
            float av[RPT];
#pragma unroll
            for (int i = 0; i < RPT; i++) av[i] = xs[kk][tr + i];
            const float4 d = *(const float4*)&wd[kk][tc];
            const float4 e = *(const float4*)&wb[kk][tc];
            const float dv[4] = {d.x, d.y, d.z, d.w};
            const float ev[4] = {e.x, e.y, e.z, e.w};
#pragma unroll
            for (int i = 0; i < RPT; i++)
#pragma unroll
                for (int j = 0; j < 4; j++) {
                    accU[i][j] += av[i] * dv[j];
                    accV[i][j] += av[i] * ev[j];
                }
        }
    }
    float bf4[4];
#pragma unroll
    for (int j = 0; j < 4; j++) bf4[j] = bias[col0 + tc + j];
#pragma unroll
    for (int i = 0; i < RPT; i++) {
        const int r = row0 + tr + i;
        if (r < Mrows) {
            const size_t orow = (size_t)r * COUT + col0 + tc;
            float4 uo = {accU[i][0] + bf4[0], accU[i][1] + bf4[1],
                         accU[i][2] + bf4[2], accU[i][3] + bf4[3]};
            *(float4*)(U + orow) = uo;
            ushort4 vh = {f2bf(accV[i][0]), f2bf(accV[i][1]),
                          f2bf(accV[i][2]), f2bf(accV[i][3])};
            *(ushort4*)(Vb + orow) = vh;
        }
    }
}

// ---------------- dense edge agg: out[i] = mean_j relu(u_i + v_j) ----------------
// bf16 V, 8 ch/lane (16B gathers), csr staged in LDS (coalesced).

template <int C, int CAP>
__global__ __launch_bounds__(256) void k_edge_agg(const float* __restrict__ U,
                                                  const ushort* __restrict__ Vb,
                                                  const int* __restrict__ offsets,
                                                  const int* __restrict__ csr,
                                                  int nbase, int nnodes,
                                                  float* __restrict__ out) {
    constexpr int TPN = C / 8;          // lanes per node (8 bf16 ch each)
    constexpr int NPB = 256 / TPN;      // nodes per block
    __shared__ int soff[NPB + 1];
    __shared__ int scsr[CAP];
    const int t = threadIdx.x;
    const int n0 = blockIdx.x * NPB;
    if (t <= NPB) {
        const int idx = min(n0 + t, nnodes);
        soff[t] = max(0, min(offsets[nbase + idx], ET));
    }
    __syncthreads();
    const int base = soff[0];
    const int tot = min(soff[NPB] - base, CAP);
    for (int k = t; k < tot; k += 256) scsr[k] = csr[base + k];
    __syncthreads();

    const int sub = t / TPN;
    const int c8 = (t % TPN) * 8;
    const int i = n0 + sub;
    if (i >= nnodes) return;
    const int beg = soff[sub];
    const int end = max(soff[sub + 1], beg);
    float u[8], acc[8] = {};
    *(float4*)&u[0] = *(const float4*)&U[(size_t)i * C + c8];
    *(float4*)&u[4] = *(const float4*)&U[(size_t)i * C + c8 + 4];
    int e = beg;
    for (; e + 4 <= end; e += 4) {
        const int o = e - base;
        const int j0 = (o     < tot) ? scsr[o]     : csr[e];
        const int j1 = (o + 1 < tot) ? scsr[o + 1] : csr[e + 1];
        const int j2 = (o + 2 < tot) ? scsr[o + 2] : csr[e + 2];
        const int j3 = (o + 3 < tot) ? scsr[o + 3] : csr[e + 3];
        const uint4 w0 = *(const uint4*)&Vb[(size_t)j0 * C + c8];
        const uint4 w1 = *(const uint4*)&Vb[(size_t)j1 * C + c8];
        const uint4 w2 = *(const uint4*)&Vb[(size_t)j2 * C + c8];
        const uint4 w3 = *(const uint4*)&Vb[(size_t)j3 * C + c8];
        acc_bf8(acc, u, w0); acc_bf8(acc, u, w1);
        acc_bf8(acc, u, w2); acc_bf8(acc, u, w3);
    }
    for (; e < end; ++e) {
        const int o = e - base;
        const int j = (o < tot) ? scsr[o] : csr[e];
        const uint4 w = *(const uint4*)&Vb[(size_t)j * C + c8];
        acc_bf8(acc, u, w);
    }
    const int dg = end - beg;
    const float inv = 1.f / (float)(dg > 0 ? dg : 1);
    float4 o0 = {acc[0] * inv, acc[1] * inv, acc[2] * inv, acc[3] * inv};
    float4 o1 = {acc[4] * inv, acc[5] * inv, acc[6] * inv, acc[7] * inv};
    *(float4*)&out[(size_t)i * C + c8] = o0;
    *(float4*)&out[(size_t)i * C + c8 + 4] = o1;
}

// ---------------- fused dual agg (Res_up output) ----------------
// Partitioned CSR: [beg, beg+vc) valid gathers; remaining cnt edges -> cnt*relu(u).
// bf16 V tables, 8 ch/lane, LDS-staged csr.

template <int C, int CAP>
__global__ __launch_bounds__(256) void k_edge_agg_fused(const float* __restrict__ U2,
                                                        const ushort* __restrict__ V2b,
                                                        const float* __restrict__ Usk,
                                                        const ushort* __restrict__ Vskb,
                                                        const float* __restrict__ b2,
                                                        const float* __restrict__ bsk,
                                                        const int* __restrict__ offsets,
                                                        const int* __restrict__ vcnt,
                                                        const int* __restrict__ csr,
                                                        int nbase, int nnodes, int nnz,
                                                        float* __restrict__ out) {
    constexpr int COUTc = C / Bn;
    constexpr int TPN = C / 8;
    constexpr int NPB = 256 / TPN;
    __shared__ int soff[NPB + 1];
    __shared__ int svc[NPB];
    __shared__ int scsr[CAP];
    const int t = threadIdx.x;
    const int n0 = blockIdx.x * NPB;
    if (t <= NPB) {
        const int idx = min(n0 + t, nnodes);
        soff[t] = max(0, min(offsets[nbase + idx], ET));
    }
    if (t < NPB) svc[t] = (n0 + t < nnodes) ? vcnt[nbase + n0 + t] : 0;
    __syncthreads();
    const int base = soff[0];
    const int tot = min(soff[NPB] - base, CAP);
    for (int k = t; k < tot; k += 256) scsr[k] = csr[base + k];
    __syncthreads();

    const int sub = t / TPN;
    const int c8 = (t % TPN) * 8;
    const int i = n0 + sub;
    if (i >= nnodes) return;
    const int beg = soff[sub];
    const int end = max(soff[sub + 1], beg);
    const int dg = end - beg;
    const int vc = max(0, min(svc[sub], dg));
    const int vend = beg + vc;
    const int cb = c8 & (COUTc - 1);
    float u2[8], usk[8];
    if (i < nnz) {
        *(float4*)&u2[0]  = *(const float4*)&U2[(size_t)i * C + c8];
        *(float4*)&u2[4]  = *(const float4*)&U2[(size_t)i * C + c8 + 4];
        *(float4*)&usk[0] = *(const float4*)&Usk[(size_t)i * C + c8];
        *(float4*)&usk[4] = *(const float4*)&Usk[(size_t)i * C + c8 + 4];
    } else {
        *(float4*)&u2[0]  = *(const float4*)&b2[cb];
        *(float4*)&u2[4]  = *(const float4*)&b2[cb + 4];
        *(float4*)&usk[0] = *(const float4*)&bsk[cb];
        *(float4*)&usk[4] = *(const float4*)&bsk[cb + 4];
    }
    float a2[8] = {}, ask[8] = {};
    int e = beg;
    for (; e + 4 <= vend; e += 4) {
        const int o = e - base;
        const int j0 = (o     < tot) ? scsr[o]     : csr[e];
        const int j1 = (o + 1 < tot) ? scsr[o + 1] : csr[e + 1];
        const int j2 = (o + 2 < tot) ? scsr[o + 2] : csr[e + 2];
        const int j3 = (o + 3 < tot) ? scsr[o + 3] : csr[e + 3];
        const uint4 p0 = *(const uint4*)&V2b[(size_t)j0 * C + c8];
        const uint4 p1 = *(const uint4*)&V2b[(size_t)j1 * C + c8];
        const uint4 p2 = *(const uint4*)&V2b[(size_t)j2 * C + c8];
        const uint4 p3 = *(const uint4*)&V2b[(size_t)j3 * C + c8];
        const uint4 q0 = *(const uint4*)&Vskb[(size_t)j0 * C + c8];
        const uint4 q1 = *(const uint4*)&Vskb[(size_t)j1 * C + c8];
        const uint4 q2 = *(const uint4*)&Vskb[(size_t)j2 * C + c8];
        const uint4 q3 = *(const uint4*)&Vskb[(size_t)j3 * C + c8];
        acc_bf8(a2, u2, p0); acc_bf8(a2, u2, p1); acc_bf8(a2, u2, p2); acc_bf8(a2, u2, p3);
        acc_bf8(ask, usk, q0); acc_bf8(ask, usk, q1); acc_bf8(ask, usk, q2); acc_bf8(ask, usk, q3);
    }
    for (; e < vend; ++e) {
        const int o = e - base;
        const int j = (o < tot) ? scsr[o] : csr[e];
        const uint4 pv = *(const uint4*)&V2b[(size_t)j * C + c8];
        const uint4 qv = *(const uint4*)&Vskb[(size_t)j * C + c8];
        acc_bf8(a2, u2, pv); acc_bf8(ask, usk, qv);
    }
    const int cnt = dg - vc;                  // edges with j >= nnz: v = 0
    if (cnt > 0) {
        const float fc = (float)cnt;
#pragma unroll
        for (int k = 0; k < 8; k++) {
            a2[k]  += fc * fmaxf(u2[k], 0.f);
            ask[k] += fc * fmaxf(usk[k], 0.f);
        }
    }
    const float inv = 1.f / (float)(dg > 0 ? dg : 1);
    float o0[8];
#pragma unroll
    for (int k = 0; k < 8; k++) o0[k] = lrelu((a2[k] + ask[k]) * inv);
    *(float4*)&out[(size_t)i * C + c8]     = *(float4*)&o0[0];
    *(float4*)&out[(size_t)i * C + c8 + 4] = *(float4*)&o0[4];
}

// ---------------- fused final agg + decoder MLP + LayerNorm(3) ----------------
// 16 nodes/block, 16 lanes/node (8 bf16 ch), LDS-staged csr; 32-row decoder.

__global__ __launch_bounds__(256) void k_agg_dec(const float* __restrict__ U,
                                                 const ushort* __restrict__ Vb,
                                                 const int* __restrict__ offsets,
                                                 const int* __restrict__ csr,
                                                 const float* __restrict__ Wd1,
                                                 const float* __restrict__ bd1,
                                                 const float* __restrict__ Wd2,
                                                 const float* __restrict__ bd2,
                                                 const float* __restrict__ gamma,
                                                 const float* __restrict__ beta,
                                                 float* __restrict__ out) {
    constexpr int C = 128;
    constexpr int CAP = 768;
    __shared__ float w1[2048];          // Wd1 [64,32]
    __shared__ float w2[96];            // Wd2 [32,3]
    __shared__ float sb1[32], sb2[3], sg[3], sbt[3];
    __shared__ float xs[32 * 66];       // 32 (n,b) rows of 64, stride 66
    __shared__ float hs[32][33];        // h1 per row
    __shared__ int soff[17];
    __shared__ int scsr[CAP];
    const int t = threadIdx.x;
    for (int i = t; i < 2048; i += 256) w1[i] = Wd1[i];
    if (t < 96) w2[t] = Wd2[t];
    if (t < 32) sb1[t] = bd1[t];
    if (t < 3) { sb2[t] = bd2[t]; sg[t] = gamma[t]; sbt[t] = beta[t]; }

    const int n0 = blockIdx.x * 16;
    if (t <= 16) {
        const int idx = min(n0 + t, N0n);
        soff[t] = max(0, min(offsets[idx], ET));
    }
    __syncthreads();
    const int base = soff[0];
    const int tot = min(soff[16] - base, CAP);
    for (int k = t; k < tot; k += 256) scsr[k] = csr[base + k];
    __syncthreads();

    // --- agg phase: 16 nodes/block, 16 thr/node, 8 bf16 ch/lane ---
    const int sub = t >> 4;
    const int c8 = (t & 15) * 8;        // channel = b*64 + k
    const int i0 = n0 + sub;
    float r[8] = {};
    if (i0 < N0n) {
        const int beg = soff[sub];
        const int end = max(soff[sub + 1], beg);
        float u[8], acc[8] = {};
        *(float4*)&u[0] = *(const float4*)&U[(size_t)i0 * C + c8];
        *(float4*)&u[4] = *(const float4*)&U[(size_t)i0 * C + c8 + 4];
        int e = beg;
        for (; e + 4 <= end; e += 4) {
            const int o = e - base;
            const int j0 = (o     < tot) ? scsr[o]     : csr[e];
            const int j1 = (o + 1 < tot) ? scsr[o + 1] : csr[e + 1];
            const int j2 = (o + 2 < tot) ? scsr[o + 2] : csr[e + 2];
            const int j3 = (o + 3 < tot) ? scsr[o + 3] : csr[e + 3];
            const uint4 w0 = *(const uint4*)&Vb[(size_t)j0 * C + c8];
            const uint4 w1v = *(const uint4*)&Vb[(size_t)j1 * C + c8];
            const uint4 w2v = *(const uint4*)&Vb[(size_t)j2 * C + c8];
            const uint4 w3 = *(const uint4*)&Vb[(size_t)j3 * C + c8];
            acc_bf8(acc, u, w0); acc_bf8(acc, u, w1v);
            acc_bf8(acc, u, w2v); acc_bf8(acc, u, w3);
        }
        for (; e < end; ++e) {
            const int o = e - base;
            const int j = (o < tot) ? scsr[o] : csr[e];
            const uint4 w = *(const uint4*)&Vb[(size_t)j * C + c8];
            acc_bf8(acc, u, w);
        }
        const int dg = end - beg;
        const float inv = 1.f / (float)(dg > 0 ? dg : 1);
#pragma unroll
        for (int k = 0; k < 8; k++) r[k] = acc[k] * inv;
    }
    // stage into LDS: row = sub*2 + b, col = k (8 entries per lane)
    {
        const int rrow = sub * 2 + (c8 >> 6);
        const int rk = c8 & 63;
        float* xp = &xs[rrow * 66 + rk];
#pragma unroll
        for (int k = 0; k < 8; k++) xp[k] = r[k];
    }
    __syncthreads();

    // --- decoder: 32 rows x 8 threads; thread computes h1[l8+8m], m=0..3 ---
    const int drow = t >> 3;
    const int l8 = t & 7;
    float h1[4] = {sb1[l8], sb1[l8 + 8], sb1[l8 + 16], sb1[l8 + 24]};
    const float* xrow = &xs[drow * 66];
#pragma unroll 8
    for (int k = 0; k < 64; k++) {
        const float xk = xrow[k];
        h1[0] += xk * w1[k * 32 + l8];
        h1[1] += xk * w1[k * 32 + l8 + 8];
        h1[2] += xk * w1[k * 32 + l8 + 16];
        h1[3] += xk * w1[k * 32 + l8 + 24];
    }
    hs[drow][l8]      = lrelu(h1[0]);
    hs[drow][l8 + 8]  = lrelu(h1[1]);
    hs[drow][l8 + 16] = lrelu(h1[2]);
    hs[drow][l8 + 24] = lrelu(h1[3]);
    __syncthreads();

    // --- h2 + LN: one thread per row ---
    if (t < 32) {
        const int node = t >> 1, b = t & 1;
        const int n = n0 + node;
        if (n < N0n) {
            float h2[3];
#pragma unroll
            for (int j = 0; j < 3; j++) {
                float s = sb2[j];
#pragma unroll
                for (int c = 0; c < 32; c++) s += hs[t][c] * w2[c * 3 + j];
                h2[j] = s;
            }
            const float mu = (h2[0] + h2[1] + h2[2]) * (1.f / 3.f);
            const float d0 = h2[0] - mu, d1 = h2[1] - mu, d2 = h2[2] - mu;
            const float var = (d0 * d0 + d1 * d1 + d2 * d2) * (1.f / 3.f);
            const float inv = rsqrtf(var + 1e-5f);
            const size_t ob = (size_t)b * N0n * 3 + (size_t)n * 3;
            out[ob + 0] = d0 * inv * sg[0] + sbt[0];
            out[ob + 1] = d1 * inv * sg[1] + sbt[1];
            out[ob + 2] = d2 * inv * sg[2] + sbt[2];
        }
    }
}

// ---------------- launch ----------------

extern "C" void kernel_launch(void* const* d_in, const int* in_sizes, int n_in,
                              void* d_out, int out_size, void* d_ws, size_t ws_size,
                              hipStream_t stream) {
    (void)in_sizes; (void)n_in; (void)out_size; (void)ws_size;
    const float* z   = (const float*)d_in[0];
    const int* g0    = (const int*)d_in[1];
    const int* g1    = (const int*)d_in[2];
    const int* g2    = (const int*)d_in[3];
    const float* W_up1 = (const float*)d_in[6];
    const float* b_up1 = (const float*)d_in[7];
    const float* W_up2 = (const float*)d_in[8];
    const float* b_up2 = (const float*)d_in[9];
    const float* Wb    = (const float*)d_in[10];
    const float* bb    = (const float*)d_in[11];
    const float* l0_W1 = (const float*)d_in[12];
    const float* l0_b1 = (const float*)d_in[13];
    const float* l0_W2 = (const float*)d_in[14];
    const float* l0_b2 = (const float*)d_in[15];
    const float* l0_Wsk = (const float*)d_in[16];
    const float* l0_bsk = (const float*)d_in[17];
    const float* l1_W1 = (const float*)d_in[18];
    const float* l1_b1 = (const float*)d_in[19];
    const float* l1_W2 = (const float*)d_in[20];
    const float* l1_b2 = (const float*)d_in[21];
    const float* l1_Wsk = (const float*)d_in[22];
    const float* l1_bsk = (const float*)d_in[23];
    const float* Wf    = (const float*)d_in[24];
    const float* bf_   = (const float*)d_in[25];
    const float* Wd1   = (const float*)d_in[26];
    const float* bd1   = (const float*)d_in[27];
    const float* Wd2   = (const float*)d_in[28];
    const float* bd2   = (const float*)d_in[29];
    const float* gamma = (const float*)d_in[30];
    const float* beta  = (const float*)d_in[31];

    char* p = (char*)d_ws;
    auto alloc = [&](size_t bytes) -> char* {
        char* r = p; p += (bytes + 255) & ~(size_t)255; return r;
    };
    int* offsets  = (int*)alloc((size_t)(NT + 1) * 4);
    int* partials = (int*)alloc((size_t)NCHUNK * 4);
    int* degcur   = (int*)alloc((size_t)3 * NT * 4);
    int* deg = degcur; int* cursor = degcur + NT; int* bcur = degcur + 2 * NT;
    int* csr = (int*)alloc((size_t)ET * 4);

    // pooled slabs: A,B,C = 12.8M floats (51.2 MB) each, D = 3.2M floats.
    // V regions are bf16 (half-occupied float granules) — offsets unchanged.
    constexpr size_t SLOT = (size_t)N0n * Bn * 64;   // 12.8M floats
    constexpr size_t M1 = 1600000;                    // 1.6M-float granule
    float* A = (float*)alloc(SLOT * 4);
    float* B = (float*)alloc(SLOT * 4);
    float* C = (float*)alloc(SLOT * 4);
    float* D = (float*)alloc((size_t)N1n * Bn * 64 * 4);

    // --- CSR build ---
    hipMemsetAsync(degcur, 0, (size_t)3 * NT * 4, stream);
    k_deg_count<<<(ET + 255) / 256, 256, 0, stream>>>(g0, g1, g2, deg);
    k_scan1<<<NCHUNK, 256, 0, stream>>>(deg, offsets, partials);
    k_scan3<<<(NT + 255) / 256, 256, 0, stream>>>(partials, offsets);
    k_csr_fill<<<(ET + 255) / 256, 256, 0, stream>>>(g0, g1, g2, offsets, cursor, bcur, csr);

    const int nb2 = N0n + N1n;   // g2 node base in offsets
    const int nb1 = N0n;         // g1 node base

    // --- latent -> x0 [N2,B,128] @ A[0,M1) ---
    float* x0 = A;
    k_latent<<<(N2n + 7) / 8, 256, 0, stream>>>(z, W_up1, b_up1, W_up2, b_up2, x0);

    // --- conv1 (g2, 128->256): U@A[M1,3M1) Vb@A[3M1,..) -> xc1 @ A[5M1,7M1) ---
    float* xc1 = A + 5 * M1;
    k_gemm_uv<128, 256, 128><<<dim3(98, 4), 256, 0, stream>>>(x0, Wb, bb,
                                                              A + M1, (ushort*)(A + 3 * M1), N2n * Bn);
    k_edge_agg<512, 256><<<(N2n + 3) / 4, 256, 0, stream>>>(A + M1, (const ushort*)(A + 3 * M1),
                                                            offsets, csr, nb2, N2n, xc1);

    // --- l0_W1 (g2, 256->64): TM=32 -> 391 blocks (was 98: 62% of CUs idle) ---
    float* t1 = A;
    k_gemm_uv<256, 64, 32><<<dim3(391, 1), 256, 0, stream>>>(xc1, l0_W1, l0_b1,
                                                             A + 7 * M1, (ushort*)(A + 7 * M1 + 800000),
                                                             N2n * Bn);
    k_edge_agg<128, 768><<<(N2n + 15) / 16, 256, 0, stream>>>(A + 7 * M1,
                                                              (const ushort*)(A + 7 * M1 + 800000),
                                                              offsets, csr, nb2, N2n, t1);

    // --- l0_W2 GEMM (64->128): TM=32 -> 782 blocks ---
    k_gemm_uv<64, 128, 32><<<dim3(391, 2), 256, 0, stream>>>(t1, l0_W2, l0_b2,
                                                             B, (ushort*)(B + M1), N2n * Bn);
    // --- skip0 GEMM (256->128): TM=32 -> 782 blocks ---
    k_gemm_uv<256, 128, 32><<<dim3(391, 2), 256, 0, stream>>>(xc1, l0_Wsk, l0_bsk,
                                                              B + 2 * M1, (ushort*)(B + 3 * M1), N2n * Bn);
    // --- fused layer0 agg (g1, C=256, nnz=N2n): -> x1 @ B[4M1,8M1) ---
    float* x1 = B + 4 * M1;
    k_edge_agg_fused<256, 512><<<(N1n + 7) / 8, 256, 0, stream>>>(B, (const ushort*)(B + M1),
                                                                  B + 2 * M1, (const ushort*)(B + 3 * M1),
                                                                  l0_b2, l0_bsk, offsets, cursor, csr,
                                                                  nb1, N1n, N2n, x1);

    // --- l1_W1 (g1, 128->64): TM=64 -> 782 blocks ---
    float* t2 = D;
    k_gemm_uv<128, 64, 64><<<dim3(782, 1), 256, 0, stream>>>(x1, l1_W1, l1_b1,
                                                             A, (ushort*)(A + 2 * M1), N1n * Bn);
    k_edge_agg<128, 768><<<(N1n + 15) / 16, 256, 0, stream>>>(A, (const ushort*)(A + 2 * M1),
                                                              offsets, csr, nb1, N1n, t2);

    // --- l1_W2 GEMM (64->64): TM=64 -> 782 blocks ---
    k_gemm_uv<64, 64, 64><<<dim3(782, 1), 256, 0, stream>>>(t2, l1_W2, l1_b2,
                                                            A, (ushort*)(A + 2 * M1), N1n * Bn);
    // --- skip1 GEMM (128->64): TM=64 -> 782 blocks ---
    k_gemm_uv<128, 64, 64><<<dim3(782, 1), 256, 0, stream>>>(x1, l1_Wsk, l1_bsk,
                                                             A + 4 * M1, (ushort*)(A + 6 * M1), N1n * Bn);
    // --- fused layer1 agg (g0, C=128, nnz=N1n): -> x2 @ C ---
    float* x2 = C;
    k_edge_agg_fused<128, 768><<<(N0n + 15) / 16, 256, 0, stream>>>(A, (const ushort*)(A + 2 * M1),
                                                                    A + 4 * M1, (const ushort*)(A + 6 * M1),
                                                                    l1_b2, l1_bsk, offsets, cursor, csr,
                                                                    0, N0n, N1n, x2);

    // --- final conv (g0, 64->64): x2 -> Uf@A (full) Vfb@B -> fused agg+decoder+LN ---
    k_gemm_uv<64, 64, 128><<<dim3(1563, 1), 256, 0, stream>>>(x2, Wf, bf_, A, (ushort*)B, N0n * Bn);
    k_agg_dec<<<(N0n + 15) / 16, 256, 0, stream>>>(A, (const ushort*)B, offsets, csr,
                                                   Wd1, bd1, Wd2, bd2, gamma, beta,
                                                   (float*)d_out);
}

// Round 8
// 510.449 us; speedup vs baseline: 1.4610x; 1.2213x over previous
//
#include <hip/hip_runtime.h>
#include <hip/hip_bf16.h>
#include <cstdint>

#define DEV_INLINE __device__ __forceinline__

// problem constants
constexpr int N0n = 100000, N1n = 25000, N2n = 6250;
constexpr int E0n = 800000, E1n = 200000, E2n = 50000;
constexpr int NT  = N0n + N1n + N2n;     // 131250 concatenated node space
constexpr int ET  = E0n + E1n + E2n;     // 1050000 concatenated edge space
constexpr int Bn  = 2;

DEV_INLINE float lrelu(float x) { return x > 0.f ? x : 0.01f * x; }

// r8: GEMMs moved to bf16 MFMA (VALU GEMM floor ~173us at 78TF; MFMA peak 2.5PF
// was idle all session). x activations + weights bf16, fp32 accum. Agg kernels
// (address-bound, r5/r6) keep fp32 U + bf16 V gathers.
DEV_INLINE ushort f2bf(float f) {
    uint32_t u = __builtin_bit_cast(uint32_t, f);
    u += 0x7FFFu + ((u >> 16) & 1u);       // round-to-nearest-even
    return (ushort)(u >> 16);
}
DEV_INLINE float bflo(uint32_t w) { return __builtin_bit_cast(float, w << 16); }
DEV_INLINE float bfhi(uint32_t w) { return __builtin_bit_cast(float, w & 0xFFFF0000u); }
DEV_INLINE uint32_t pack2(float a, float b) {
    return (uint32_t)f2bf(a) | ((uint32_t)f2bf(b) << 16);
}

// acc[k] += relu(u[k] + v[k]) for 8 bf16 channels packed in a uint4
DEV_INLINE void acc_bf8(float* acc, const float* u, const uint4 w) {
    acc[0] += fmaxf(u[0] + bflo(w.x), 0.f);
    acc[1] += fmaxf(u[1] + bfhi(w.x), 0.f);
    acc[2] += fmaxf(u[2] + bflo(w.y), 0.f);
    acc[3] += fmaxf(u[3] + bfhi(w.y), 0.f);
    acc[4] += fmaxf(u[4] + bflo(w.z), 0.f);
    acc[5] += fmaxf(u[5] + bfhi(w.z), 0.f);
    acc[6] += fmaxf(u[6] + bflo(w.w), 0.f);
    acc[7] += fmaxf(u[7] + bfhi(w.w), 0.f);
}

typedef short bf16x8 __attribute__((ext_vector_type(8)));
typedef float f32x4 __attribute__((ext_vector_type(4)));

// ---------------- CSR build (3 graphs concatenated) ----------------

__global__ __launch_bounds__(256) void k_deg_count(const int* __restrict__ g0,
                                                   const int* __restrict__ g1,
                                                   const int* __restrict__ g2,
                                                   int* __restrict__ deg) {
    int e = blockIdx.x * 256 + threadIdx.x;
    int gd = -1;
    if (e < E0n)                gd = g0[E0n + e] % N0n;
    else if (e < E0n + E1n)     gd = N0n + (g1[E1n + (e - E0n)] % N1n);
    else if (e < ET)            gd = N0n + N1n + (g2[E2n + (e - E0n - E1n)] % N2n);
    if (gd >= 0 && gd < NT) atomicAdd(&deg[gd], 1);
}

constexpr int SCAN_CHUNK = 2048;
constexpr int NCHUNK = (NT + SCAN_CHUNK - 1) / SCAN_CHUNK;   // 65

__global__ __launch_bounds__(256) void k_scan1(const int* __restrict__ deg,
                                               int* __restrict__ out,
                                               int* __restrict__ partials) {
    __shared__ int sums[256];
    const int chunk = blockIdx.x, t = threadIdx.x;
    const int base = chunk * SCAN_CHUNK + t * 8;
    int v[8]; int s = 0;
#pragma unroll
    for (int i = 0; i < 8; i++) { int idx = base + i; v[i] = (idx < NT) ? deg[idx] : 0; s += v[i]; }
    int val = s;
    sums[t] = val; __syncthreads();
    for (int off = 1; off < 256; off <<= 1) {
        int y = (t >= off) ? sums[t - off] : 0;
        __syncthreads();
        val += y; sums[t] = val;
        __syncthreads();
    }
    const int excl = val - s;
    if (t == 255) partials[chunk] = val;
    int run = excl;
#pragma unroll
    for (int i = 0; i < 8; i++) { int idx = base + i; if (idx < NT) out[idx] = run; run += v[i]; }
}

// scan2 folded in: each block redundantly prefix-sums the 65 partials in LDS.
__global__ __launch_bounds__(256) void k_scan3(const int* __restrict__ partials,
                                               int* __restrict__ offsets) {
    __shared__ int s[NCHUNK];
    __shared__ int pre[NCHUNK + 1];
    const int t = threadIdx.x;
    if (t < NCHUNK) s[t] = partials[t];
    __syncthreads();
    if (t == 0) {
        int run = 0;
        for (int i = 0; i < NCHUNK; i++) { pre[i] = run; run += s[i]; }
        pre[NCHUNK] = run;
    }
    __syncthreads();
    const int idx = blockIdx.x * 256 + t;
    if (idx < NT) offsets[idx] += pre[idx / SCAN_CHUNK];
    if (idx == 0) offsets[NT] = pre[NCHUNK];   // == ET
}

// Partitioned fill: valid-unpool sources at segment front; cursor[] = valid count.
__global__ __launch_bounds__(256) void k_csr_fill(const int* __restrict__ g0,
                                                  const int* __restrict__ g1,
                                                  const int* __restrict__ g2,
                                                  const int* __restrict__ offsets,
                                                  int* __restrict__ cursor,
                                                  int* __restrict__ bcur,
                                                  int* __restrict__ csr) {
    int e = blockIdx.x * 256 + threadIdx.x;
    int src, gd; bool front;
    if (e < E0n)            { src = g0[e] % N0n;      gd = g0[E0n + e] % N0n;                 front = src < N1n; }
    else if (e < E0n + E1n) { int le = e - E0n;       src = g1[le] % N1n; gd = N0n + (g1[E1n + le] % N1n); front = src < N2n; }
    else if (e < ET)        { int le = e - E0n - E1n; src = g2[le] % N2n; gd = N0n + N1n + (g2[E2n + le] % N2n); front = true; }
    else return;
    int pos = front ? offsets[gd] + atomicAdd(&cursor[gd], 1)
                    : offsets[gd + 1] - 1 - atomicAdd(&bcur[gd], 1);
    if (pos >= 0 && pos < ET) csr[pos] = src;   // local src id
}

// ---------------- weight prep: W[2K][COUT] fp32 -> Wt[2*COUT][K] bf16 ----------------
// Wt rows [0,COUT) = (Wa-Wb)^T, rows [COUT,2COUT) = Wb^T. One launch, 8 sets.

__global__ __launch_bounds__(256) void k_wprep(const float* W0, ushort* T0,
                                               const float* W1, ushort* T1,
                                               const float* W2, ushort* T2,
                                               const float* W3, ushort* T3,
                                               const float* W4, ushort* T4,
                                               const float* W5, ushort* T5,
                                               const float* W6, ushort* T6,
                                               const float* W7, ushort* T7) {
    constexpr int KS[8] = {128, 256, 64, 256, 128, 64, 128, 64};
    constexpr int CS[8] = {256, 64, 128, 128, 64, 64, 64, 64};
    const int set = blockIdx.x >> 5;          // 32 blocks / set
    const int blk = blockIdx.x & 31;
    const float* W; ushort* T;
    switch (set) {
        case 0: W = W0; T = T0; break;
        case 1: W = W1; T = T1; break;
        case 2: W = W2; T = T2; break;
        case 3: W = W3; T = T3; break;
        case 4: W = W4; T = T4; break;
        case 5: W = W5; T = T5; break;
        case 6: W = W6; T = T6; break;
        default: W = W7; T = T7; break;
    }
    const int K = KS[set], C = CS[set];
    const int tot = 2 * C * K;
    for (int idx = blk * 256 + threadIdx.x; idx < tot; idx += 32 * 256) {
        const int n = idx / K, k = idx % K;
        float v;
        if (n < C) v = W[(size_t)k * C + n] - W[(size_t)(K + k) * C + n];
        else       v = W[(size_t)(K + k) * C + (n - C)];
        T[idx] = f2bf(v);
    }
}

// ---------------- latent MLP: z -> x0 bf16 [N2*B, 128] ----------------

__global__ __launch_bounds__(256) void k_latent(const float* __restrict__ z,
                                                const float* __restrict__ W1,
                                                const float* __restrict__ b1,
                                                const float* __restrict__ W2,
                                                const float* __restrict__ b2,
                                                ushort* __restrict__ x0b) {
    __shared__ float col[64];
    const int t = threadIdx.x;
    const int b = t >> 7, l = t & 127;
    const float zv = z[b * 128 + l];
    float h1[64];
#pragma unroll
    for (int k = 0; k < 64; k++) h1[k] = lrelu(zv * W1[k] + b1[k]);
    for (int nn = 0; nn < 8; nn++) {
        const int n = blockIdx.x * 8 + nn;
        if (n >= N2n) break;                 // uniform across block
        if (t < 64) col[t] = W2[t * N2n + n];
        __syncthreads();
        float s = b2[n];
#pragma unroll
        for (int k = 0; k < 64; k++) s += h1[k] * col[k];
        x0b[((size_t)n * Bn + b) * 128 + l] = f2bf(s);
        __syncthreads();
    }
}

// ---------------- MFMA GEMM: D = x_bf @ [Wd | Wb]; U fp32 (+bias), V bf16 ----------
// 4 waves = 2x2 wave grid; wave = 32x32 via 2x2 mfma_f32_16x16x32_bf16 frags.
// A staged in LDS [64][40] (80B row stride: 16B-aligned, 20-word bank rotation).
// B frags straight from Wt global (16B/lane, L1/L2-resident weights).
// Same (lane,reg)->k map for A and B => result invariant to k-permutation.

template <int K, int COUT>
__global__ __launch_bounds__(256) void k_gemm_mfma(const ushort* __restrict__ xb,
                                                   const ushort* __restrict__ Wt,
                                                   const float* __restrict__ bias,
                                                   float* __restrict__ U,
                                                   ushort* __restrict__ Vb,
                                                   int Mrows) {
    constexpr int BM = 64;
    __shared__ ushort As[64][40];
    const int t = threadIdx.x;
    const int lane = t & 63;
    const int wave = t >> 6;
    const int wr = wave >> 1, wc = wave & 1;
    const int row0 = blockIdx.x * BM;
    const int col0 = blockIdx.y * 64;        // in [0, 2*COUT)
    const int l15 = lane & 15;
    const int kg = lane >> 4;                // 0..3
    const int srow = t >> 2;                 // staging: 4 thr/row
    const int sseg = (t & 3) * 8;            // 8 bf16 = 16B
    f32x4 acc[2][2] = {};

    for (int k0 = 0; k0 < K; k0 += 32) {
        __syncthreads();
        {
            uint4 a = {0, 0, 0, 0};
            const int gr = row0 + srow;
            if (gr < Mrows) a = *(const uint4*)&xb[(size_t)gr * K + k0 + sseg];
            *(uint4*)&As[srow][sseg] = a;
        }
        __syncthreads();
        bf16x8 af[2], bfr[2];
#pragma unroll
        for (int fi = 0; fi < 2; fi++)
            af[fi] = *(const bf16x8*)&As[wr * 32 + fi * 16 + l15][kg * 8];
#pragma unroll
        for (int fj = 0; fj < 2; fj++) {
            const int c = col0 + wc * 32 + fj * 16 + l15;
            bfr[fj] = *(const bf16x8*)&Wt[(size_t)c * K + k0 + kg * 8];
        }
#pragma unroll
        for (int fi = 0; fi < 2; fi++)
#pragma unroll
            for (int fj = 0; fj < 2; fj++)
                acc[fi][fj] = __builtin_amdgcn_mfma_f32_16x16x32_bf16(
                    af[fi], bfr[fj], acc[fi][fj], 0, 0, 0);
    }
    // D layout (m89-verified): col = lane&15, row = (lane>>4)*4 + reg
    const bool isU = col0 < COUT;
#pragma unroll
    for (int fi = 0; fi < 2; fi++) {
#pragma unroll
        for (int fj = 0; fj < 2; fj++) {
            const int c = col0 + wc * 32 + fj * 16 + l15;
#pragma unroll
            for (int r = 0; r < 4; r++) {
                const int row = row0 + wr * 32 + fi * 16 + kg * 4 + r;
                if (row < Mrows) {
                    if (isU) U[(size_t)row * COUT + c] = acc[fi][fj][r] + bias[c];
                    else     Vb[(size_t)row * COUT + (c - COUT)] = f2bf(acc[fi][fj][r]);
                }
            }
        }
    }
}

// ---------------- dense edge agg: out_bf16[i] = mean_j relu(u_i + v_j) ------------
// bf16 V, 8 ch/lane (16B gathers), csr staged in LDS (r6: address-bound fix).

template <int C, int CAP>
__global__ __launch_bounds__(256) void k_edge_agg(const float* __restrict__ U,
                                                  const ushort* __restrict__ Vb,
                                                  const int* __restrict__ offsets,
                                                  const int* __restrict__ csr,
                                                  int nbase, int nnodes,
                                                  ushort* __restrict__ outb) {
    constexpr int TPN = C / 8;          // lanes per node (8 bf16 ch each)
    constexpr int NPB = 256 / TPN;      // nodes per block
    __shared__ int soff[NPB + 1];
    __shared__ int scsr[CAP];
    const int t = threadIdx.x;
    const int n0 = blockIdx.x * NPB;
    if (t <= NPB) {
        const int idx = min(n0 + t, nnodes);
        soff[t] = max(0, min(offsets[nbase + idx], ET));
    }
    __syncthreads();
    const int base = soff[0];
    const int tot = min(soff[NPB] - base, CAP);
    for (int k = t; k < tot; k += 256) scsr[k] = csr[base + k];
    __syncthreads();

    const int sub = t / TPN;
    const int c8 = (t % TPN) * 8;
    const int i = n0 + sub;
    if (i >= nnodes) return;
    const int beg = soff[sub];
    const int end = max(soff[sub + 1], beg);
    float u[8], acc[8] = {};
    *(float4*)&u[0] = *(const float4*)&U[(size_t)i * C + c8];
    *(float4*)&u[4] = *(const float4*)&U[(size_t)i * C + c8 + 4];
    int e = beg;
    for (; e + 4 <= end; e += 4) {
        const int o = e - base;
        const int j0 = (o     < tot) ? scsr[o]     : csr[e];
        const int j1 = (o + 1 < tot) ? scsr[o + 1] : csr[e + 1];
        const int j2 = (o + 2 < tot) ? scsr[o + 2] : csr[e + 2];
        const int j3 = (o + 3 < tot) ? scsr[o + 3] : csr[e + 3];
        const uint4 w0 = *(const uint4*)&Vb[(size_t)j0 * C + c8];
        const uint4 w1 = *(const uint4*)&Vb[(size_t)j1 * C + c8];
        const uint4 w2 = *(const uint4*)&Vb[(size_t)j2 * C + c8];
        const uint4 w3 = *(const uint4*)&Vb[(size_t)j3 * C + c8];
        acc_bf8(acc, u, w0); acc_bf8(acc, u, w1);
        acc_bf8(acc, u, w2); acc_bf8(acc, u, w3);
    }
    for (; e < end; ++e) {
        const int o = e - base;
        const int j = (o < tot) ? scsr[o] : csr[e];
        const uint4 w = *(const uint4*)&Vb[(size_t)j * C + c8];
        acc_bf8(acc, u, w);
    }
    const int dg = end - beg;
    const float inv = 1.f / (float)(dg > 0 ? dg : 1);
    uint4 o;
    o.x = pack2(acc[0] * inv, acc[1] * inv);
    o.y = pack2(acc[2] * inv, acc[3] * inv);
    o.z = pack2(acc[4] * inv, acc[5] * inv);
    o.w = pack2(acc[6] * inv, acc[7] * inv);
    *(uint4*)&outb[(size_t)i * C + c8] = o;
}

// ---------------- fused dual agg (Res_up output), bf16 out ----------------
// Partitioned CSR: [beg, beg+vc) valid gathers; remaining cnt edges -> cnt*relu(u).

template <int C, int CAP>
__global__ __launch_bounds__(256) void k_edge_agg_fused(const float* __restrict__ U2,
                                                        const ushort* __restrict__ V2b,
                                                        const float* __restrict__ Usk,
                                                        const ushort* __restrict__ Vskb,
                                                        const float* __restrict__ b2,
                                                        const float* __restrict__ bsk,
                                                        const int* __restrict__ offsets,
                                                        const int* __restrict__ vcnt,
                                                        const int* __restrict__ csr,
                                                        int nbase, int nnodes, int nnz,
                                                        ushort* __restrict__ outb) {
    constexpr int COUTc = C / Bn;
    constexpr int TPN = C / 8;
    constexpr int NPB = 256 / TPN;
    __shared__ int soff[NPB + 1];
    __shared__ int svc[NPB];
    __shared__ int scsr[CAP];
    const int t = threadIdx.x;
    const int n0 = blockIdx.x * NPB;
    if (t <= NPB) {
        const int idx = min(n0 + t, nnodes);
        soff[t] = max(0, min(offsets[nbase + idx], ET));
    }
    if (t < NPB) svc[t] = (n0 + t < nnodes) ? vcnt[nbase + n0 + t] : 0;
    __syncthreads();
    const int base = soff[0];
    const int tot = min(soff[NPB] - base, CAP);
    for (int k = t; k < tot; k += 256) scsr[k] = csr[base + k];
    __syncthreads();

    const int sub = t / TPN;
    const int c8 = (t % TPN) * 8;
    const int i = n0 + sub;
    if (i >= nnodes) return;
    const int beg = soff[sub];
    const int end = max(soff[sub + 1], beg);
    const int dg = end - beg;
    const int vc = max(0, min(svc[sub], dg));
    const int vend = beg + vc;
    const int cb = c8 & (COUTc - 1);
    float u2[8], usk[8];
    if (i < nnz) {
        *(float4*)&u2[0]  = *(const float4*)&U2[(size_t)i * C + c8];
        *(float4*)&u2[4]  = *(const float4*)&U2[(size_t)i * C + c8 + 4];
        *(float4*)&usk[0] = *(const float4*)&Usk[(size_t)i * C + c8];
        *(float4*)&usk[4] = *(const float4*)&Usk[(size_t)i * C + c8 + 4];
    } else {
        *(float4*)&u2[0]  = *(const float4*)&b2[cb];
        *(float4*)&u2[4]  = *(const float4*)&b2[cb + 4];
        *(float4*)&usk[0] = *(const float4*)&bsk[cb];
        *(float4*)&usk[4] = *(const float4*)&bsk[cb + 4];
    }
    float a2[8] = {}, ask[8] = {};
    int e = beg;
    for (; e + 4 <= vend; e += 4) {
        const int o = e - base;
        const int j0 = (o     < tot) ? scsr[o]     : csr[e];
        const int j1 = (o + 1 < tot) ? scsr[o + 1] : csr[e + 1];
        const int j2 = (o + 2 < tot) ? scsr[o + 2] : csr[e + 2];
        const int j3 = (o + 3 < tot) ? scsr[o + 3] : csr[e + 3];
        const uint4 p0 = *(const uint4*)&V2b[(size_t)j0 * C + c8];
        const uint4 p1 = *(const uint4*)&V2b[(size_t)j1 * C + c8];
        const uint4 p2 = *(const uint4*)&V2b[(size_t)j2 * C + c8];
        const uint4 p3 = *(const uint4*)&V2b[(size_t)j3 * C + c8];
        const uint4 q0 = *(const uint4*)&Vskb[(size_t)j0 * C + c8];
        const uint4 q1 = *(const uint4*)&Vskb[(size_t)j1 * C + c8];
        const uint4 q2 = *(const uint4*)&Vskb[(size_t)j2 * C + c8];
        const uint4 q3 = *(const uint4*)&Vskb[(size_t)j3 * C + c8];
        acc_bf8(a2, u2, p0); acc_bf8(a2, u2, p1); acc_bf8(a2, u2, p2); acc_bf8(a2, u2, p3);
        acc_bf8(ask, usk, q0); acc_bf8(ask, usk, q1); acc_bf8(ask, usk, q2); acc_bf8(ask, usk, q3);
    }
    for (; e < vend; ++e) {
        const int o = e - base;
        const int j = (o < tot) ? scsr[o] : csr[e];
        const uint4 pv = *(const uint4*)&V2b[(size_t)j * C + c8];
        const uint4 qv = *(const uint4*)&Vskb[(size_t)j * C + c8];
        acc_bf8(a2, u2, pv); acc_bf8(ask, usk, qv);
    }
    const int cnt = dg - vc;                  // edges with j >= nnz: v = 0
    if (cnt > 0) {
        const float fc = (float)cnt;
#pragma unroll
        for (int k = 0; k < 8; k++) {
            a2[k]  += fc * fmaxf(u2[k], 0.f);
            ask[k] += fc * fmaxf(usk[k], 0.f);
        }
    }
    const float inv = 1.f / (float)(dg > 0 ? dg : 1);
    float ov[8];
#pragma unroll
    for (int k = 0; k < 8; k++) ov[k] = lrelu((a2[k] + ask[k]) * inv);
    uint4 o;
    o.x = pack2(ov[0], ov[1]); o.y = pack2(ov[2], ov[3]);
    o.z = pack2(ov[4], ov[5]); o.w = pack2(ov[6], ov[7]);
    *(uint4*)&outb[(size_t)i * C + c8] = o;
}

// ---------------- fused final agg + decoder MLP + LayerNorm(3) ----------------
// 16 nodes/block, 16 lanes/node (8 bf16 ch), LDS-staged csr; 32-row decoder.

__global__ __launch_bounds__(256) void k_agg_dec(const float* __restrict__ U,
                                                 const ushort* __restrict__ Vb,
                                                 const int* __restrict__ offsets,
                                                 const int* __restrict__ csr,
                                                 const float* __restrict__ Wd1,
                                                 const float* __restrict__ bd1,
                                                 const float* __restrict__ Wd2,
                                                 const float* __restrict__ bd2,
                                                 const float* __restrict__ gamma,
                                                 const float* __restrict__ beta,
                                                 float* __restrict__ out) {
    constexpr int C = 128;
    constexpr int CAP = 768;
    __shared__ float w1[2048];          // Wd1 [64,32]
    __shared__ float w2[96];            // Wd2 [32,3]
    __shared__ float sb1[32], sb2[3], sg[3], sbt[3];
    __shared__ float xs[32 * 66];       // 32 (n,b) rows of 64, stride 66
    __shared__ float hs[32][33];        // h1 per row
    __shared__ int soff[17];
    __shared__ int scsr[CAP];
    const int t = threadIdx.x;
    for (int i = t; i < 2048; i += 256) w1[i] = Wd1[i];
    if (t < 96) w2[t] = Wd2[t];
    if (t < 32) sb1[t] = bd1[t];
    if (t < 3) { sb2[t] = bd2[t]; sg[t] = gamma[t]; sbt[t] = beta[t]; }

    const int n0 = blockIdx.x * 16;
    if (t <= 16) {
        const int idx = min(n0 + t, N0n);
        soff[t] = max(0, min(offsets[idx], ET));
    }
    __syncthreads();
    const int base = soff[0];
    const int tot = min(soff[16] - base, CAP);
    for (int k = t; k < tot; k += 256) scsr[k] = csr[base + k];
    __syncthreads();

    // --- agg phase: 16 nodes/block, 16 thr/node, 8 bf16 ch/lane ---
    const int sub = t >> 4;
    const int c8 = (t & 15) * 8;        // channel = b*64 + k
    const int i0 = n0 + sub;
    float r[8] = {};
    if (i0 < N0n) {
        const int beg = soff[sub];
        const int end = max(soff[sub + 1], beg);
        float u[8], acc[8] = {};
        *(float4*)&u[0] = *(const float4*)&U[(size_t)i0 * C + c8];
        *(float4*)&u[4] = *(const float4*)&U[(size_t)i0 * C + c8 + 4];
        int e = beg;
        for (; e + 4 <= end; e += 4) {
            const int o = e - base;
            const int j0 = (o     < tot) ? scsr[o]     : csr[e];
            const int j1 = (o + 1 < tot) ? scsr[o + 1] : csr[e + 1];
            const int j2 = (o + 2 < tot) ? scsr[o + 2] : csr[e + 2];
            const int j3 = (o + 3 < tot) ? scsr[o + 3] : csr[e + 3];
            const uint4 w0 = *(const uint4*)&Vb[(size_t)j0 * C + c8];
            const uint4 w1v = *(const uint4*)&Vb[(size_t)j1 * C + c8];
            const uint4 w2v = *(const uint4*)&Vb[(size_t)j2 * C + c8];
            const uint4 w3 = *(const uint4*)&Vb[(size_t)j3 * C + c8];
            acc_bf8(acc, u, w0); acc_bf8(acc, u, w1v);
            acc_bf8(acc, u, w2v); acc_bf8(acc, u, w3);
        }
        for (; e < end; ++e) {
            const int o = e - base;
            const int j = (o < tot) ? scsr[o] : csr[e];
            const uint4 w = *(const uint4*)&Vb[(size_t)j * C + c8];
            acc_bf8(acc, u, w);
        }
        const int dg = end - beg;
        const float inv = 1.f / (float)(dg > 0 ? dg : 1);
#pragma unroll
        for (int k = 0; k < 8; k++) r[k] = acc[k] * inv;
    }
    // stage into LDS: row = sub*2 + b, col = k (8 entries per lane)
    {
        const int rrow = sub * 2 + (c8 >> 6);
        const int rk = c8 & 63;
        float* xp = &xs[rrow * 66 + rk];
#pragma unroll
        for (int k = 0; k < 8; k++) xp[k] = r[k];
    }
    __syncthreads();

    // --- decoder: 32 rows x 8 threads; thread computes h1[l8+8m], m=0..3 ---
    const int drow = t >> 3;
    const int l8 = t & 7;
    float h1[4] = {sb1[l8], sb1[l8 + 8], sb1[l8 + 16], sb1[l8 + 24]};
    const float* xrow = &xs[drow * 66];
#pragma unroll 8
    for (int k = 0; k < 64; k++) {
        const float xk = xrow[k];
        h1[0] += xk * w1[k * 32 + l8];
        h1[1] += xk * w1[k * 32 + l8 + 8];
        h1[2] += xk * w1[k * 32 + l8 + 16];
        h1[3] += xk * w1[k * 32 + l8 + 24];
    }
    hs[drow][l8]      = lrelu(h1[0]);
    hs[drow][l8 + 8]  = lrelu(h1[1]);
    hs[drow][l8 + 16] = lrelu(h1[2]);
    hs[drow][l8 + 24] = lrelu(h1[3]);
    __syncthreads();

    // --- h2 + LN: one thread per row ---
    if (t < 32) {
        const int node = t >> 1, b = t & 1;
        const int n = n0 + node;
        if (n < N0n) {
            float h2[3];
#pragma unroll
            for (int j = 0; j < 3; j++) {
                float s = sb2[j];
#pragma unroll
                for (int c = 0; c < 32; c++) s += hs[t][c] * w2[c * 3 + j];
                h2[j] = s;
            }
            const float mu = (h2[0] + h2[1] + h2[2]) * (1.f / 3.f);
            const float d0 = h2[0] - mu, d1 = h2[1] - mu, d2 = h2[2] - mu;
            const float var = (d0 * d0 + d1 * d1 + d2 * d2) * (1.f / 3.f);
            const float inv = rsqrtf(var + 1e-5f);
            const size_t ob = (size_t)b * N0n * 3 + (size_t)n * 3;
            out[ob + 0] = d0 * inv * sg[0] + sbt[0];
            out[ob + 1] = d1 * inv * sg[1] + sbt[1];
            out[ob + 2] = d2 * inv * sg[2] + sbt[2];
        }
    }
}

// ---------------- launch ----------------

extern "C" void kernel_launch(void* const* d_in, const int* in_sizes, int n_in,
                              void* d_out, int out_size, void* d_ws, size_t ws_size,
                              hipStream_t stream) {
    (void)in_sizes; (void)n_in; (void)out_size; (void)ws_size;
    const float* z   = (const float*)d_in[0];
    const int* g0    = (const int*)d_in[1];
    const int* g1    = (const int*)d_in[2];
    const int* g2    = (const int*)d_in[3];
    const float* W_up1 = (const float*)d_in[6];
    const float* b_up1 = (const float*)d_in[7];
    const float* W_up2 = (const float*)d_in[8];
    const float* b_up2 = (const float*)d_in[9];
    const float* Wb    = (const float*)d_in[10];
    const float* bb    = (const float*)d_in[11];
    const float* l0_W1 = (const float*)d_in[12];
    const float* l0_b1 = (const float*)d_in[13];
    const float* l0_W2 = (const float*)d_in[14];
    const float* l0_b2 = (const float*)d_in[15];
    const float* l0_Wsk = (const float*)d_in[16];
    const float* l0_bsk = (const float*)d_in[17];
    const float* l1_W1 = (const float*)d_in[18];
    const float* l1_b1 = (const float*)d_in[19];
    const float* l1_W2 = (const float*)d_in[20];
    const float* l1_b2 = (const float*)d_in[21];
    const float* l1_Wsk = (const float*)d_in[22];
    const float* l1_bsk = (const float*)d_in[23];
    const float* Wf    = (const float*)d_in[24];
    const float* bf_   = (const float*)d_in[25];
    const float* Wd1   = (const float*)d_in[26];
    const float* bd1   = (const float*)d_in[27];
    const float* Wd2   = (const float*)d_in[28];
    const float* bd2   = (const float*)d_in[29];
    const float* gamma = (const float*)d_in[30];
    const float* beta  = (const float*)d_in[31];

    char* p = (char*)d_ws;
    auto alloc = [&](size_t bytes) -> char* {
        char* r = p; p += (bytes + 255) & ~(size_t)255; return r;
    };
    int* offsets  = (int*)alloc((size_t)(NT + 1) * 4);
    int* partials = (int*)alloc((size_t)NCHUNK * 4);
    int* degcur   = (int*)alloc((size_t)3 * NT * 4);
    int* deg = degcur; int* cursor = degcur + NT; int* bcur = degcur + 2 * NT;
    int* csr = (int*)alloc((size_t)ET * 4);

    // bf16 weight buffers (Wt[2*COUT][K]) for the 8 MFMA GEMMs
    ushort* Wt0 = (ushort*)alloc(65536 * 2);   // conv1  K=128 C=256
    ushort* Wt1 = (ushort*)alloc(32768 * 2);   // l0_W1  K=256 C=64
    ushort* Wt2 = (ushort*)alloc(16384 * 2);   // l0_W2  K=64  C=128
    ushort* Wt3 = (ushort*)alloc(65536 * 2);   // skip0  K=256 C=128
    ushort* Wt4 = (ushort*)alloc(16384 * 2);   // l1_W1  K=128 C=64
    ushort* Wt5 = (ushort*)alloc(8192 * 2);    // l1_W2  K=64  C=64
    ushort* Wt6 = (ushort*)alloc(16384 * 2);   // skip1  K=128 C=64
    ushort* Wt7 = (ushort*)alloc(8192 * 2);    // final  K=64  C=64

    // pooled slabs: A,B,C = 12.8M floats (51.2 MB) each, D = 3.2M floats.
    // x activations + V tables are bf16 (half-occupied granules) — offsets kept.
    constexpr size_t SLOT = (size_t)N0n * Bn * 64;   // 12.8M floats
    constexpr size_t M1 = 1600000;                    // 1.6M-float granule
    float* A = (float*)alloc(SLOT * 4);
    float* B = (float*)alloc(SLOT * 4);
    float* C = (float*)alloc(SLOT * 4);
    float* D = (float*)alloc((size_t)N1n * Bn * 64 * 4);

    // --- CSR build + weight prep ---
    hipMemsetAsync(degcur, 0, (size_t)3 * NT * 4, stream);
    k_wprep<<<256, 256, 0, stream>>>(Wb, Wt0, l0_W1, Wt1, l0_W2, Wt2, l0_Wsk, Wt3,
                                     l1_W1, Wt4, l1_W2, Wt5, l1_Wsk, Wt6, Wf, Wt7);
    k_deg_count<<<(ET + 255) / 256, 256, 0, stream>>>(g0, g1, g2, deg);
    k_scan1<<<NCHUNK, 256, 0, stream>>>(deg, offsets, partials);
    k_scan3<<<(NT + 255) / 256, 256, 0, stream>>>(partials, offsets);
    k_csr_fill<<<(ET + 255) / 256, 256, 0, stream>>>(g0, g1, g2, offsets, cursor, bcur, csr);

    const int nb2 = N0n + N1n;   // g2 node base in offsets
    const int nb1 = N0n;         // g1 node base

    // --- latent -> x0 bf16 [12500,128] @ A[0,M1) ---
    ushort* x0b = (ushort*)A;
    k_latent<<<(N2n + 7) / 8, 256, 0, stream>>>(z, W_up1, b_up1, W_up2, b_up2, x0b);

    // --- conv1 (g2, 128->256): U@A[M1,3M1) Vb@A[3M1,..) -> xc1 bf16 @ A[5M1,..) ---
    ushort* xc1b = (ushort*)(A + 5 * M1);
    k_gemm_mfma<128, 256><<<dim3(196, 8), 256, 0, stream>>>(x0b, Wt0, bb,
                                                            A + M1, (ushort*)(A + 3 * M1), N2n * Bn);
    k_edge_agg<512, 256><<<(N2n + 3) / 4, 256, 0, stream>>>(A + M1, (const ushort*)(A + 3 * M1),
                                                            offsets, csr, nb2, N2n, xc1b);

    // --- l0_W1 (g2, 256->64): -> t1 bf16 @ A[0,M1) (x0 dead) ---
    ushort* t1b = (ushort*)A;
    k_gemm_mfma<256, 64><<<dim3(196, 2), 256, 0, stream>>>(xc1b, Wt1, l0_b1,
                                                           A + 7 * M1, (ushort*)(A + 7 * M1 + 800000),
                                                           N2n * Bn);
    k_edge_agg<128, 768><<<(N2n + 15) / 16, 256, 0, stream>>>(A + 7 * M1,
                                                              (const ushort*)(A + 7 * M1 + 800000),
                                                              offsets, csr, nb2, N2n, t1b);

    // --- l0_W2 (64->128): U2@B[0,M1) V2b@B[M1,..) ---
    k_gemm_mfma<64, 128><<<dim3(196, 4), 256, 0, stream>>>(t1b, Wt2, l0_b2,
                                                           B, (ushort*)(B + M1), N2n * Bn);
    // --- skip0 (256->128): Usk@B[2M1,3M1) Vskb@B[3M1,..) ---
    k_gemm_mfma<256, 128><<<dim3(196, 4), 256, 0, stream>>>(xc1b, Wt3, l0_bsk,
                                                            B + 2 * M1, (ushort*)(B + 3 * M1), N2n * Bn);
    // --- fused layer0 agg (g1, C=256, nnz=N2n): -> x1 bf16 @ B[4M1,..) ---
    ushort* x1b = (ushort*)(B + 4 * M1);
    k_edge_agg_fused<256, 512><<<(N1n + 7) / 8, 256, 0, stream>>>(B, (const ushort*)(B + M1),
                                                                  B + 2 * M1, (const ushort*)(B + 3 * M1),
                                                                  l0_b2, l0_bsk, offsets, cursor, csr,
                                                                  nb1, N1n, N2n, x1b);

    // --- l1_W1 (g1, 128->64): U@A[0,2M1) Vb@A[2M1,..) -> t2 bf16 @ D ---
    ushort* t2b = (ushort*)D;
    k_gemm_mfma<128, 64><<<dim3(782, 2), 256, 0, stream>>>(x1b, Wt4, l1_b1,
                                                           A, (ushort*)(A + 2 * M1), N1n * Bn);
    k_edge_agg<128, 768><<<(N1n + 15) / 16, 256, 0, stream>>>(A, (const ushort*)(A + 2 * M1),
                                                              offsets, csr, nb1, N1n, t2b);

    // --- l1_W2 (64->64): U2@A[0,2M1) V2b@A[2M1,..) ---
    k_gemm_mfma<64, 64><<<dim3(782, 2), 256, 0, stream>>>(t2b, Wt5, l1_b2,
                                                          A, (ushort*)(A + 2 * M1), N1n * Bn);
    // --- skip1 (128->64): Usk@A[4M1,6M1) Vskb@A[6M1,..) ---
    k_gemm_mfma<128, 64><<<dim3(782, 2), 256, 0, stream>>>(x1b, Wt6, l1_bsk,
                                                           A + 4 * M1, (ushort*)(A + 6 * M1), N1n * Bn);
    // --- fused layer1 agg (g0, C=128, nnz=N1n): -> x2 bf16 @ C ---
    ushort* x2b = (ushort*)C;
    k_edge_agg_fused<128, 768><<<(N0n + 15) / 16, 256, 0, stream>>>(A, (const ushort*)(A + 2 * M1),
                                                                    A + 4 * M1, (const ushort*)(A + 6 * M1),
                                                                    l1_b2, l1_bsk, offsets, cursor, csr,
                                                                    0, N0n, N1n, x2b);

    // --- final conv (g0, 64->64): x2 -> Uf fp32 @ A (full), Vfb bf16 @ B ---
    k_gemm_mfma<64, 64><<<dim3(3125, 2), 256, 0, stream>>>(x2b, Wt7, bf_, A, (ushort*)B, N0n * Bn);
    // --- fused final agg + decoder + LN -> d_out ---
    k_agg_dec<<<(N0n + 15) / 16, 256, 0, stream>>>(A, (const ushort*)B, offsets, csr,
                                                   Wd1, bd1, Wd2, bd2, gamma, beta,
                                                   (float*)d_out);
}